// Round 4
// baseline (2466.720 us; speedup 1.0000x reference)
//
#include <hip/hip_runtime.h>
#include <math.h>

// ---------------------------------------------------------------------------
// GCN link predictor on MI355X, round 12.
// Round-11 post-mortem: feature-slicing made agg WORSE (73us, FETCH 216MB) --
// adjacent slices overlap in flight (2x3.2MB > 4MB/XCD L2) and csr re-walk
// added VALU. Round 12 restructures aggregation:
//   - dst buckets shrink to 128 nodes (NBK=391); within each bucket the edge
//     segment is sorted by src>>10 (49 x ~1MB phases) at build time.
//   - agg: one block per (bucket, feature-half). 128 nodes x 64 feats f32
//     accumulator in LDS (32KB static). Waves walk the phase-sorted segment
//     linearly (2 edges per wave-gather, 128B half-row each), ds_add_f32
//     into LDS (2-way bank alias = free). Concurrent blocks walk phases at
//     similar rates -> gathers cluster in ~1-2MB src window -> L2-resident.
//     Each edge touched once per half; no sync, no re-reads, no extra VALU.
//   - accumulation order changes (f32 reorder ~1e-6, inside 0.0039 absmax).
// Kept: factored edge head (zh GEMM + light per-edge), prep_all, MFMA GEMMs,
// LDS-bucketed graph build (now 512-wide hists for NBK=391).
// ---------------------------------------------------------------------------

typedef __attribute__((ext_vector_type(8))) short short8x;
typedef __attribute__((ext_vector_type(8))) _Float16 half8x;
typedef __attribute__((ext_vector_type(4))) float f32x4;

__device__ __forceinline__ unsigned short f2bf(float f) {
  unsigned int u = __float_as_uint(f);
  unsigned int r = u + 0x7FFFu + ((u >> 16) & 1u);  // RNE
  return (unsigned short)(r >> 16);
}
__device__ __forceinline__ unsigned short f2h(float f) {
  union { _Float16 h; unsigned short u; } cv;
  cv.h = (_Float16)f;  // v_cvt_f16_f32, RNE
  return cv.u;
}

// ------------------------------ graph build --------------------------------

__global__ void zero_int_kernel(int* __restrict__ p, int n) {
  int i = blockIdx.x * blockDim.x + threadIdx.x;
  if (i < n) p[i] = 0;
}

// Per-block LDS histogram over buckets (col>>7, 128-node buckets, NBK<=512);
// one global atomic per (block,bucket). 4096 edges/block.
__global__ __launch_bounds__(256) void binA_hist_kernel(const int* __restrict__ col,
                                                        int* __restrict__ bucket_count, int E,
                                                        int NBK) {
  __shared__ int hist[512];
  const int tid = threadIdx.x;
  hist[tid] = 0;
  hist[tid + 256] = 0;
  __syncthreads();
  const int base = blockIdx.x * 4096;
#pragma unroll
  for (int j = 0; j < 16; ++j) {
    int i = base + j * 256 + tid;
    if (i < E) atomicAdd(&hist[((unsigned int)col[i]) >> 7], 1);
  }
  __syncthreads();
  for (int k = tid; k < NBK; k += 256) {
    int h = hist[k];
    if (h) atomicAdd(&bucket_count[k], h);
  }
}

// Single block (512 threads): exclusive scan of NBK (<=512) bucket counts.
__global__ __launch_bounds__(512) void scan_buckets_kernel(const int* __restrict__ bucket_count,
                                                           int* __restrict__ bucket_start,
                                                           int* __restrict__ bcur, int NBK,
                                                           int E) {
  __shared__ int ws[8];
  const int tid = threadIdx.x;
  const int lane = tid & 63;
  const int wid = tid >> 6;
  int v = (tid < NBK) ? bucket_count[tid] : 0;
  int incl = v;
#pragma unroll
  for (int d = 1; d < 64; d <<= 1) {
    int t = __shfl_up(incl, d, 64);
    if (lane >= d) incl += t;
  }
  if (lane == 63) ws[wid] = incl;
  __syncthreads();
  int woff = 0;
#pragma unroll
  for (int w = 0; w < 8; ++w)
    if (w < wid) woff += ws[w];
  int excl = woff + incl - v;
  if (tid < NBK) {
    bucket_start[tid] = excl;
    bcur[tid] = excl;
  }
  if (tid == 0) bucket_start[NBK] = E;
}

// binA_scatter: 4096 edges/block; LDS hist -> one global atomicAdd per
// (block,bucket) reserve -> LDS-cursor scatter of packed (col<<16|row).
__global__ __launch_bounds__(256) void binA_scatter_kernel(const int* __restrict__ row,
                                                           const int* __restrict__ col,
                                                           int* __restrict__ bcur,
                                                           unsigned int* __restrict__ staging,
                                                           int E, int NBK) {
  __shared__ int hist[512];
  const int tid = threadIdx.x;
  hist[tid] = 0;
  hist[tid + 256] = 0;
  __syncthreads();
  const int base = blockIdx.x * 4096;
  unsigned int payload[16];
  int bk[16];
#pragma unroll
  for (int j = 0; j < 16; ++j) {
    int i = base + j * 256 + tid;
    if (i < E) {
      unsigned int c = (unsigned int)__builtin_nontemporal_load(&col[i]);
      unsigned int r = (unsigned int)__builtin_nontemporal_load(&row[i]);
      payload[j] = (c << 16) | r;
      bk[j] = (int)(c >> 7);
      atomicAdd(&hist[bk[j]], 1);
    } else {
      bk[j] = -1;
    }
  }
  __syncthreads();
  for (int k = tid; k < NBK; k += 256) {
    int h = hist[k];
    hist[k] = h ? atomicAdd(&bcur[k], h) : 0;
  }
  __syncthreads();
#pragma unroll
  for (int j = 0; j < 16; ++j) {
    if (bk[j] >= 0) {
      int p = atomicAdd(&hist[bk[j]], 1);
      staging[p] = payload[j];
    }
  }
}

// binB1: one block per 128-node bucket: degree count -> dinv.
__global__ __launch_bounds__(256) void binB1_kernel(const unsigned int* __restrict__ staging,
                                                    const int* __restrict__ bucket_start,
                                                    float* __restrict__ dinv, int N) {
  __shared__ int cnt1[128];
  const int b = blockIdx.x;
  const int tid = threadIdx.x;
  if (tid < 128) cnt1[tid] = 0;
  __syncthreads();
  const int s = bucket_start[b];
  const int e = bucket_start[b + 1];
  for (int t = s + tid; t < e; t += 256) {
    atomicAdd(&cnt1[(staging[t] >> 16) & 127u], 1);
  }
  __syncthreads();
  if (tid < 128) {
    int i = b * 128 + tid;
    if (i < N) dinv[i] = rsqrtf((float)cnt1[tid] + 1.0f);
  }
}

// binB2: per-bucket (phase=src>>10, node) LDS histogram + scan -> scatter
// into phase-major sorted csrW (bf16 dinv[src]<<16 | src) + csrD (dst local).
__global__ __launch_bounds__(256) void binB2_kernel(const unsigned int* __restrict__ staging,
                                                    const int* __restrict__ bucket_start,
                                                    const float* __restrict__ dinv,
                                                    unsigned int* __restrict__ csrW,
                                                    unsigned char* __restrict__ csrD) {
  __shared__ int cnt[64 * 128];  // 32 KB: [phase][cl]
  __shared__ int ws[4];
  const int b = blockIdx.x;
  const int tid = threadIdx.x;
  for (int k = tid; k < 64 * 128; k += 256) cnt[k] = 0;
  __syncthreads();
  const int s = bucket_start[b];
  const int e = bucket_start[b + 1];
  for (int t = s + tid; t < e; t += 256) {
    unsigned int v = __builtin_nontemporal_load(&staging[t]);
    int cl = (int)((v >> 16) & 127u);
    int ph = (int)((v & 0xFFFFu) >> 10);
    atomicAdd(&cnt[ph * 128 + cl], 1);
  }
  __syncthreads();
  // exclusive scan of 8192 counters: 32 per thread, then block scan of sums.
  const int base32 = tid * 32;
  int tsum = 0;
#pragma unroll
  for (int k = 0; k < 32; ++k) tsum += cnt[base32 + k];
  const int lane = tid & 63;
  const int wid = tid >> 6;
  int incl = tsum;
#pragma unroll
  for (int d = 1; d < 64; d <<= 1) {
    int t = __shfl_up(incl, d, 64);
    if (lane >= d) incl += t;
  }
  if (lane == 63) ws[wid] = incl;
  __syncthreads();
  int woff = 0;
#pragma unroll
  for (int w = 0; w < 4; ++w)
    if (w < wid) woff += ws[w];
  int run = woff + incl - tsum;
#pragma unroll
  for (int k = 0; k < 32; ++k) {
    int c = cnt[base32 + k];
    cnt[base32 + k] = run;
    run += c;
  }
  __syncthreads();
  for (int t = s + tid; t < e; t += 256) {
    unsigned int v = __builtin_nontemporal_load(&staging[t]);
    int cl = (int)((v >> 16) & 127u);
    unsigned int src = v & 0xFFFFu;
    int ph = (int)(src >> 10);
    int p = s + atomicAdd(&cnt[ph * 128 + cl], 1);
    csrW[p] = (((unsigned int)f2bf(dinv[src])) << 16) | src;
    csrD[p] = (unsigned char)cl;
  }
}

// --------------------- weight prep: fragment ordering ----------------------
__global__ __launch_bounds__(256) void prep_all_kernel(const float* __restrict__ W1,
                                                       const float* __restrict__ W2,
                                                       const float* __restrict__ hW1,
                                                       unsigned short* __restrict__ bfW1,
                                                       unsigned short* __restrict__ bfW2,
                                                       unsigned short* __restrict__ bfH) {
  int idx = blockIdx.x * blockDim.x + threadIdx.x;
  const float* W;
  unsigned short* out;
  int K, N, base, mode;
  if (idx < 8192) {
    W = W1; out = bfW1; K = 512; N = 128; base = 0; mode = 0;
  } else if (idx < 9216) {
    W = W2; out = bfW2; K = 128; N = 64; base = 8192; mode = 0;
  } else if (idx < 10240) {
    W = hW1; out = bfH; K = 64; N = 128; base = 9216; mode = 1;
  } else {
    return;
  }
  int id = idx - base;
  int lane = id & 63;
  int t = id >> 6;
  int KS = K / 32;
  int ks = t % KS;
  int nt = t / KS;
  int n = nt * 16 + (lane & 15);
  int k0 = ks * 32 + (lane >> 4) * 8;
  unsigned short* o = out + (size_t)id * 8;
#pragma unroll
  for (int j = 0; j < 8; ++j) {
    int k = k0 + j;
    float v;
    if (mode == 0)
      v = W[(size_t)k * N + n];
    else
      v = (n < 64) ? W[(size_t)k * 64 + n] : W[(size_t)(64 + k) * 64 + (n - 64)];
    o[j] = f2bf(v);
  }
}

// ------------------------------- MFMA GEMM ---------------------------------
template <int K, int N, bool ABF16, bool OUTF16>
__global__ __launch_bounds__(256) void mfma_gemm_kernel(const void* __restrict__ Ap,
                                                        const unsigned short* __restrict__ Bfrag,
                                                        unsigned short* __restrict__ Cout, int M) {
  constexpr int KS = K / 32;
  constexpr int NT = N / 16;
  const int lane = threadIdx.x & 63;
  const int wid = threadIdx.x >> 6;
  const int quad = lane >> 4;
  const int lc = lane & 15;
  const int mbase = blockIdx.x * 128 + wid * 32;
  if (mbase >= M) return;

  f32x4 acc[2][NT];
#pragma unroll
  for (int mt = 0; mt < 2; ++mt)
#pragma unroll
    for (int nt = 0; nt < NT; ++nt) acc[mt][nt] = (f32x4){0.f, 0.f, 0.f, 0.f};

  int r0 = mbase + lc;
  int r1 = mbase + 16 + lc;
  if (r0 >= M) r0 = M - 1;
  if (r1 >= M) r1 = M - 1;

#pragma unroll
  for (int ks = 0; ks < KS; ++ks) {
    const int k0 = ks * 32 + quad * 8;
    short8x a[2];
    if constexpr (ABF16) {
      const unsigned short* A = (const unsigned short*)Ap;
      a[0] = *(const short8x*)(A + (size_t)r0 * K + k0);
      a[1] = *(const short8x*)(A + (size_t)r1 * K + k0);
    } else {
      const float* A = (const float*)Ap;
      const float4* p0 = (const float4*)(A + (size_t)r0 * K + k0);
      const float4* p1 = (const float4*)(A + (size_t)r1 * K + k0);
      float4 u0 = p0[0], v0 = p0[1];
      float4 u1 = p1[0], v1 = p1[1];
      short8x t0, t1;
      t0[0] = (short)f2bf(u0.x); t0[1] = (short)f2bf(u0.y);
      t0[2] = (short)f2bf(u0.z); t0[3] = (short)f2bf(u0.w);
      t0[4] = (short)f2bf(v0.x); t0[5] = (short)f2bf(v0.y);
      t0[6] = (short)f2bf(v0.z); t0[7] = (short)f2bf(v0.w);
      t1[0] = (short)f2bf(u1.x); t1[1] = (short)f2bf(u1.y);
      t1[2] = (short)f2bf(u1.z); t1[3] = (short)f2bf(u1.w);
      t1[4] = (short)f2bf(v1.x); t1[5] = (short)f2bf(v1.y);
      t1[6] = (short)f2bf(v1.z); t1[7] = (short)f2bf(v1.w);
      a[0] = t0;
      a[1] = t1;
    }
#pragma unroll
    for (int nt = 0; nt < NT; ++nt) {
      short8x b = *(const short8x*)(Bfrag + (((size_t)nt * KS + ks) * 64 + lane) * 8);
      acc[0][nt] = __builtin_amdgcn_mfma_f32_16x16x32_bf16(a[0], b, acc[0][nt], 0, 0, 0);
      acc[1][nt] = __builtin_amdgcn_mfma_f32_16x16x32_bf16(a[1], b, acc[1][nt], 0, 0, 0);
    }
  }

#pragma unroll
  for (int mt = 0; mt < 2; ++mt)
#pragma unroll
    for (int nt = 0; nt < NT; ++nt)
#pragma unroll
      for (int reg = 0; reg < 4; ++reg) {
        int row = mbase + mt * 16 + quad * 4 + reg;
        if (row < M) {
          float v = acc[mt][nt][reg];
          Cout[(size_t)row * N + nt * 16 + lc] = OUTF16 ? f2h(v) : f2bf(v);
        }
      }
}

// ----------------- aggregation (bucket-block LDS accumulate) ----------------
// One block per (128-node dst bucket, 64-feature half). RD = dwords per full
// row (64 for F=128, 32 for F=64). fo = blockIdx.y*32 dword offset.
// 1024 threads = 16 waves; each wave gathers 2 edges at once (32 dwords =
// 128B half-row each) from the phase-sorted segment and ds_add_f32's into
// the 128x64 f32 LDS accumulator (banks: li%32 -> 2-way alias, free).
template <int RD>
__global__ __launch_bounds__(1024) void agg_bucket_kernel(
    const unsigned short* __restrict__ xw, const unsigned int* __restrict__ csrW,
    const unsigned char* __restrict__ csrD, const int* __restrict__ bucket_start,
    const float* __restrict__ dinv, const float* __restrict__ bias,
    const float* __restrict__ gamma, const float* __restrict__ beta,
    const float* __restrict__ mean, const float* __restrict__ var,
    unsigned short* __restrict__ out, int N) {
  constexpr int CH = 8;  // edges per chunk per wave
  __shared__ float accum[128 * 64];  // 32 KB
  const int b = blockIdx.x;
  const int fo = blockIdx.y * 32;  // dword offset within row
  const int tid = threadIdx.x;
  for (int k = tid; k < 128 * 64; k += 1024) accum[k] = 0.f;
  __syncthreads();
  const int S = bucket_start[b];
  const int Eb = bucket_start[b + 1];
  const int wv = tid >> 6;
  const int lane = tid & 63;
  const int sub = lane >> 5;   // which of the 2 edges this lane serves
  const int li = lane & 31;    // dword within half-row
  const unsigned int* xw32 = (const unsigned int*)xw;

  for (int base = S + wv * CH; base < Eb; base += 16 * CH) {
    unsigned int ew[CH];
    int ed[CH];
#pragma unroll
    for (int j = 0; j < CH; ++j) {
      int t = base + j;
      if (t > Eb - 1) t = Eb - 1;
      ew[j] = __builtin_nontemporal_load(&csrW[t]);
      ed[j] = (int)__builtin_nontemporal_load(&csrD[t]);
    }
    unsigned int gv[CH / 2];
    unsigned int ee[CH / 2];
    int cc[CH / 2];
    int vvb[CH / 2];
#pragma unroll
    for (int jj = 0; jj < CH / 2; ++jj) {
      unsigned int e = sub ? ew[2 * jj + 1] : ew[2 * jj];
      int c = sub ? ed[2 * jj + 1] : ed[2 * jj];
      ee[jj] = e;
      cc[jj] = c;
      vvb[jj] = (base + 2 * jj + sub) < Eb;
      gv[jj] = xw32[(size_t)(e & 0xFFFFu) * RD + fo + li];
    }
#pragma unroll
    for (int jj = 0; jj < CH / 2; ++jj) {
      float w = vvb[jj] ? __uint_as_float(ee[jj] & 0xFFFF0000u) : 0.f;
      float xl = __uint_as_float(gv[jj] << 16);
      float xh = __uint_as_float(gv[jj] & 0xFFFF0000u);
      unsafeAtomicAdd(&accum[cc[jj] * 64 + li], w * xl);
      unsafeAtomicAdd(&accum[cc[jj] * 64 + 32 + li], w * xh);
    }
  }
  __syncthreads();
  // finalize: 128 nodes x 32 dwords = 4096 (cl, li) pairs
  for (int id = tid; id < 128 * 32; id += 1024) {
    int cl = id >> 5;
    int fi = id & 31;
    int i = b * 128 + cl;
    if (i >= N) continue;
    float di = dinv[i];
    float accL = accum[cl * 64 + fi];
    float accH = accum[cl * 64 + 32 + fi];
    unsigned int sv = xw32[(size_t)i * RD + fo + fi];
    int f0 = 2 * (fo + fi), f1 = f0 + 1;
    float v0 = di * accL + di * di * __uint_as_float(sv << 16) + bias[f0];
    float v1 = di * accH + di * di * __uint_as_float(sv & 0xFFFF0000u) + bias[f1];
    v0 = (v0 - mean[f0]) * rsqrtf(var[f0] + 1e-5f) * gamma[f0] + beta[f0];
    v1 = (v1 - mean[f1]) * rsqrtf(var[f1] + 1e-5f) * gamma[f1] + beta[f1];
    unsigned int packed =
        (unsigned int)f2bf(fmaxf(v0, 0.f)) | ((unsigned int)f2bf(fmaxf(v1, 0.f)) << 16);
    ((unsigned int*)out)[(size_t)i * RD + fo + fi] = packed;
  }
}

// ------------------------------- edge head ---------------------------------
__global__ __launch_bounds__(256) void head2_kernel(
    const unsigned short* __restrict__ zh, const int* __restrict__ src,
    const int* __restrict__ dst, const float* __restrict__ hb1,
    const float* __restrict__ hw2, const float* __restrict__ hb2,
    float* __restrict__ out, int P) {
  const int lane = threadIdx.x & 63;
  const int lc = lane & 15;
  const int quad = lane >> 4;
  float b1v[16], w2v[16];
#pragma unroll
  for (int t = 0; t < 16; ++t) {
    b1v[t] = hb1[quad * 16 + t];
    w2v[t] = hw2[quad * 16 + t];
  }
  const float bias2 = hb2[0];
  const int nchunks = (P + 15) / 16;
  const int gw = blockIdx.x * 4 + (threadIdx.x >> 6);
  const int nw = gridDim.x * 4;

  for (int ch = gw; ch < nchunks; ch += nw) {
    int p = ch * 16 + lc;
    int pc = p < P ? p : P - 1;
    int s = __builtin_nontemporal_load(&src[pc]);
    int d = __builtin_nontemporal_load(&dst[pc]);
    const half8x* pa = (const half8x*)(zh + (size_t)s * 128 + quad * 16);
    const half8x* pb = (const half8x*)(zh + (size_t)d * 128 + 64 + quad * 16);
    half8x a0 = pa[0], a1 = pa[1];
    half8x b0 = pb[0], b1 = pb[1];
    float acc = 0.f;
#pragma unroll
    for (int t = 0; t < 8; ++t) {
      float hm = fmaxf((float)a0[t] + (float)b0[t] + b1v[t], 0.f);
      acc = fmaf(hm, w2v[t], acc);
    }
#pragma unroll
    for (int t = 0; t < 8; ++t) {
      float hm = fmaxf((float)a1[t] + (float)b1[t] + b1v[8 + t], 0.f);
      acc = fmaf(hm, w2v[8 + t], acc);
    }
    acc += __shfl_xor(acc, 16, 64);
    acc += __shfl_xor(acc, 32, 64);
    if (quad == 0 && p < P) {
      float o = 1.0f / (1.0f + __expf(-(acc + bias2)));
      __builtin_nontemporal_store(o, &out[p]);
    }
  }
}

// ------------------------------- launcher ----------------------------------

extern "C" void kernel_launch(void* const* d_in, const int* in_sizes, int n_in,
                              void* d_out, int out_size, void* d_ws, size_t ws_size,
                              hipStream_t stream) {
  const float* x = (const float*)d_in[0];
  const int* ei = (const int*)d_in[1];
  const int* src = (const int*)d_in[2];
  const int* dst = (const int*)d_in[3];
  const float* W1 = (const float*)d_in[4];
  const float* b1 = (const float*)d_in[5];
  const float* g1 = (const float*)d_in[6];
  const float* be1 = (const float*)d_in[7];
  const float* mu1 = (const float*)d_in[8];
  const float* va1 = (const float*)d_in[9];
  const float* W2 = (const float*)d_in[10];
  const float* b2 = (const float*)d_in[11];
  const float* g2 = (const float*)d_in[12];
  const float* be2 = (const float*)d_in[13];
  const float* mu2 = (const float*)d_in[14];
  const float* va2 = (const float*)d_in[15];
  const float* hW1 = (const float*)d_in[16];
  const float* hb1 = (const float*)d_in[17];
  const float* hW2 = (const float*)d_in[18];
  const float* hb2 = (const float*)d_in[19];
  float* out = (float*)d_out;

  const int N = in_sizes[0] / 512;
  const int E = in_sizes[1] / 2;
  const int P = in_sizes[2];
  const int* row = ei;
  const int* col = ei + E;
  const int NBK = (N + 127) / 128;    // 128-node buckets, <=512
  const int NAB = (E + 4095) / 4096;  // binA blocks

  char* wp = (char*)d_ws;
  auto alloc = [&](size_t bytes) {
    char* p = wp;
    wp += (bytes + 255) & ~(size_t)255;
    return p;
  };
  unsigned short* xw1 = (unsigned short*)alloc((size_t)N * 128 * 2);
  unsigned short* h = (unsigned short*)alloc((size_t)N * 128 * 2);
  unsigned short* xw2 = (unsigned short*)alloc((size_t)N * 64 * 2);
  unsigned short* z = (unsigned short*)alloc((size_t)N * 64 * 2);
  unsigned short* zh = (unsigned short*)alloc((size_t)N * 128 * 2);  // f16 [za||zb]
  float* dinv = (float*)alloc((size_t)N * 4);
  unsigned int* csrW = (unsigned int*)alloc((size_t)E * 4);
  unsigned char* csrD = (unsigned char*)alloc((size_t)E);
  unsigned int* staging = (unsigned int*)alloc((size_t)E * 4);
  int* bucket_count = (int*)alloc((size_t)NBK * 4);
  int* bucket_start = (int*)alloc((size_t)(NBK + 1) * 4);
  int* bcur = (int*)alloc((size_t)NBK * 4);
  unsigned short* bfW1 = (unsigned short*)alloc(512 * 128 * 2);
  unsigned short* bfW2 = (unsigned short*)alloc(128 * 64 * 2);
  unsigned short* bfH = (unsigned short*)alloc(128 * 64 * 2);
  (void)ws_size;
  (void)n_in;
  (void)out_size;

  // --- graph structure ---
  hipLaunchKernelGGL(zero_int_kernel, dim3((NBK + 255) / 256), dim3(256), 0, stream, bucket_count,
                     NBK);
  hipLaunchKernelGGL(binA_hist_kernel, dim3(NAB), dim3(256), 0, stream, col, bucket_count, E, NBK);
  hipLaunchKernelGGL(scan_buckets_kernel, dim3(1), dim3(512), 0, stream, bucket_count,
                     bucket_start, bcur, NBK, E);
  hipLaunchKernelGGL(binA_scatter_kernel, dim3(NAB), dim3(256), 0, stream, row, col, bcur, staging,
                     E, NBK);
  hipLaunchKernelGGL(binB1_kernel, dim3(NBK), dim3(256), 0, stream, staging, bucket_start, dinv,
                     N);
  hipLaunchKernelGGL(binB2_kernel, dim3(NBK), dim3(256), 0, stream, staging, bucket_start, dinv,
                     csrW, csrD);

  // --- weight fragment prep (single kernel) ---
  hipLaunchKernelGGL(prep_all_kernel, dim3(40), dim3(256), 0, stream, W1, W2, hW1, bfW1, bfW2,
                     bfH);

  // --- layer 1 ---
  hipLaunchKernelGGL((mfma_gemm_kernel<512, 128, false, false>), dim3((N + 127) / 128), dim3(256),
                     0, stream, x, bfW1, xw1, N);
  hipLaunchKernelGGL((agg_bucket_kernel<64>), dim3(NBK, 2), dim3(1024), 0, stream, xw1, csrW,
                     csrD, bucket_start, dinv, b1, g1, be1, mu1, va1, h, N);

  // --- layer 2 ---
  hipLaunchKernelGGL((mfma_gemm_kernel<128, 64, true, false>), dim3((N + 127) / 128), dim3(256), 0,
                     stream, h, bfW2, xw2, N);
  hipLaunchKernelGGL((agg_bucket_kernel<32>), dim3(NBK, 1), dim3(1024), 0, stream, xw2, csrW,
                     csrD, bucket_start, dinv, b2, g2, be2, mu2, va2, z, N);

  // --- edge head: node-side GEMM then per-edge add/relu/dot ---
  hipLaunchKernelGGL((mfma_gemm_kernel<64, 128, true, true>), dim3((N + 127) / 128), dim3(256), 0,
                     stream, z, bfH, zh, N);
  hipLaunchKernelGGL(head2_kernel, dim3(2048), dim3(256), 0, stream, zh, src, dst, hb1, hW2, hb2,
                     out, P);
}

// Round 5
// 410.229 us; speedup vs baseline: 6.0130x; 6.0130x over previous
//
#include <hip/hip_runtime.h>
#include <math.h>

// ---------------------------------------------------------------------------
// GCN link predictor on MI355X, round 13.
// Round-12 post-mortem: LDS-atomic bucket accumulate was a 20x regression
// (VALUBusy 4.4%, same-address ds-atomic serialization from dst-sorted edge
// pairs). Reverted agg to round-10's 16-deep gather kernel (verified 61us).
// Round 13 keeps r12's locality goal but moves it entirely into the build:
// binB2 now emits each node's CSR segment SORTED BY SRC (2-key counting
// scatter over [src>>10 phase][dst local] in 64KB LDS, ph-major layout so
// the scan is bank-conflict-free). Concurrent nodes' 16-deep walks then
// all gather from the same ~1MB src-quantile window -> L2-resident, with
// zero changes to the hot agg kernel. f32 reorder only (~1e-7).
// Kept from round 10: factored edge head (zh GEMM + light per-edge),
// prep_all, 256-node-bucket build, bf16 MFMA GEMMs, agg_fast.
// ---------------------------------------------------------------------------

typedef __attribute__((ext_vector_type(8))) short short8x;
typedef __attribute__((ext_vector_type(8))) _Float16 half8x;
typedef __attribute__((ext_vector_type(4))) float f32x4;

__device__ __forceinline__ unsigned short f2bf(float f) {
  unsigned int u = __float_as_uint(f);
  unsigned int r = u + 0x7FFFu + ((u >> 16) & 1u);  // RNE
  return (unsigned short)(r >> 16);
}
__device__ __forceinline__ unsigned short f2h(float f) {
  union { _Float16 h; unsigned short u; } cv;
  cv.h = (_Float16)f;  // v_cvt_f16_f32, RNE
  return cv.u;
}

// ------------------------------ graph build --------------------------------

__global__ void zero_int_kernel(int* __restrict__ p, int n) {
  int i = blockIdx.x * blockDim.x + threadIdx.x;
  if (i < n) p[i] = 0;
}

// Per-block LDS histogram over buckets (col>>8); one global atomic per
// (block,bucket). 4096 edges/block.
__global__ __launch_bounds__(256) void binA_hist_kernel(const int* __restrict__ col,
                                                        int* __restrict__ bucket_count, int E,
                                                        int NBK) {
  __shared__ int hist[256];
  const int tid = threadIdx.x;
  hist[tid] = 0;
  __syncthreads();
  const int base = blockIdx.x * 4096;
#pragma unroll
  for (int j = 0; j < 16; ++j) {
    int i = base + j * 256 + tid;
    if (i < E) atomicAdd(&hist[((unsigned int)col[i]) >> 8], 1);
  }
  __syncthreads();
  if (tid < NBK) {
    int h = hist[tid];
    if (h) atomicAdd(&bucket_count[tid], h);
  }
}

// Single block: exclusive scan of NBK (<=256) bucket counts.
__global__ __launch_bounds__(256) void scan_buckets_kernel(const int* __restrict__ bucket_count,
                                                           int* __restrict__ bucket_start,
                                                           int* __restrict__ bcur,
                                                           int* __restrict__ offs_n, int NBK,
                                                           int E) {
  __shared__ int ws[4];
  const int tid = threadIdx.x;
  const int lane = tid & 63;
  const int wid = tid >> 6;
  int v = (tid < NBK) ? bucket_count[tid] : 0;
  int incl = v;
#pragma unroll
  for (int d = 1; d < 64; d <<= 1) {
    int t = __shfl_up(incl, d, 64);
    if (lane >= d) incl += t;
  }
  if (lane == 63) ws[wid] = incl;
  __syncthreads();
  int woff = 0;
#pragma unroll
  for (int w = 0; w < 4; ++w)
    if (w < wid) woff += ws[w];
  int excl = woff + incl - v;
  if (tid < NBK) {
    bucket_start[tid] = excl;
    bcur[tid] = excl;
  }
  if (tid == 0) {
    bucket_start[NBK] = E;
    *offs_n = E;
  }
}

// binA_scatter: 4096 edges/block; LDS hist -> one global atomicAdd per
// (block,bucket) reserve -> LDS-cursor scatter of packed (col<<16|row).
__global__ __launch_bounds__(256) void binA_scatter_kernel(const int* __restrict__ row,
                                                           const int* __restrict__ col,
                                                           int* __restrict__ bcur,
                                                           unsigned int* __restrict__ staging,
                                                           int E, int NBK) {
  __shared__ int hist[256];
  const int tid = threadIdx.x;
  hist[tid] = 0;
  __syncthreads();
  const int base = blockIdx.x * 4096;
  unsigned int payload[16];
  int bk[16];
#pragma unroll
  for (int j = 0; j < 16; ++j) {
    int i = base + j * 256 + tid;
    if (i < E) {
      unsigned int c = (unsigned int)__builtin_nontemporal_load(&col[i]);
      unsigned int r = (unsigned int)__builtin_nontemporal_load(&row[i]);
      payload[j] = (c << 16) | r;
      bk[j] = (int)(c >> 8);
      atomicAdd(&hist[bk[j]], 1);
    } else {
      bk[j] = -1;
    }
  }
  __syncthreads();
  if (tid < NBK) {
    int h = hist[tid];
    hist[tid] = h ? atomicAdd(&bcur[tid], h) : 0;
  }
  __syncthreads();
#pragma unroll
  for (int j = 0; j < 16; ++j) {
    if (bk[j] >= 0) {
      int p = atomicAdd(&hist[bk[j]], 1);
      staging[p] = payload[j];
    }
  }
}

// binB1: one block per 256-node bucket. LDS node-histogram of the bucket's
// staging segment -> LDS scan -> writes offs[node] and dinv[node].
__global__ __launch_bounds__(256) void binB1_kernel(const unsigned int* __restrict__ staging,
                                                    const int* __restrict__ bucket_start,
                                                    int* __restrict__ offs,
                                                    float* __restrict__ dinv, int N) {
  __shared__ int cnt[256];
  __shared__ int ws[4];
  const int b = blockIdx.x;
  const int n0 = b * 256;
  const int tid = threadIdx.x;
  cnt[tid] = 0;
  __syncthreads();
  const int s = bucket_start[b];
  const int e = bucket_start[b + 1];
  for (int t = s + tid; t < e; t += 256) {
    atomicAdd(&cnt[(staging[t] >> 16) & 255u], 1);
  }
  __syncthreads();
  const int deg = cnt[tid];
  const int lane = tid & 63;
  const int wid = tid >> 6;
  int incl = deg;
#pragma unroll
  for (int d = 1; d < 64; d <<= 1) {
    int t = __shfl_up(incl, d, 64);
    if (lane >= d) incl += t;
  }
  if (lane == 63) ws[wid] = incl;
  __syncthreads();
  int woff = 0;
#pragma unroll
  for (int w = 0; w < 4; ++w)
    if (w < wid) woff += ws[w];
  const int excl = woff + incl - deg;
  const int node = n0 + tid;
  if (node < N) {
    offs[node] = s + excl;
    dinv[node] = rsqrtf((float)deg + 1.0f);
  }
}

// binB2: 2-key counting scatter -> CSR with per-node segments SORTED BY SRC
// phase (src>>10, 49 phases < 64). Counter layout [ph][cl] (ph-major) keeps
// the per-cl serial scan conflict-free (thread tid = cl reads cnt[k*256+tid],
// bank = tid&31). Entry format unchanged: bf16(dinv[src])<<16 | src.
__global__ __launch_bounds__(256) void binB2_kernel(const unsigned int* __restrict__ staging,
                                                    const int* __restrict__ bucket_start,
                                                    const float* __restrict__ dinv,
                                                    unsigned int* __restrict__ csr) {
  __shared__ int cnt[64 * 256];  // 64 KB: [ph][cl]
  __shared__ int ws[4];
  const int b = blockIdx.x;
  const int tid = threadIdx.x;
  for (int k = tid; k < 64 * 256; k += 256) cnt[k] = 0;
  __syncthreads();
  const int s = bucket_start[b];
  const int e = bucket_start[b + 1];
  for (int t = s + tid; t < e; t += 256) {
    unsigned int v = __builtin_nontemporal_load(&staging[t]);
    int cl = (int)((v >> 16) & 255u);
    int ph = (int)((v & 0xFFFFu) >> 10);
    atomicAdd(&cnt[ph * 256 + cl], 1);
  }
  __syncthreads();
  // thread tid = local node cl. deg = sum over phases.
  int deg = 0;
#pragma unroll
  for (int k = 0; k < 64; ++k) deg += cnt[k * 256 + tid];
  // block exclusive scan of deg over cl
  const int lane = tid & 63;
  const int wid = tid >> 6;
  int incl = deg;
#pragma unroll
  for (int d = 1; d < 64; d <<= 1) {
    int t = __shfl_up(incl, d, 64);
    if (lane >= d) incl += t;
  }
  if (lane == 63) ws[wid] = incl;
  __syncthreads();
  int woff = 0;
#pragma unroll
  for (int w = 0; w < 4; ++w)
    if (w < wid) woff += ws[w];
  int pos = s + woff + incl - deg;  // global start of node cl's segment
  // turn counts into running global cursors (cl-major, ph-minor order)
#pragma unroll
  for (int k = 0; k < 64; ++k) {
    int c = cnt[k * 256 + tid];
    cnt[k * 256 + tid] = pos;
    pos += c;
  }
  __syncthreads();
  for (int t = s + tid; t < e; t += 256) {
    unsigned int v = __builtin_nontemporal_load(&staging[t]);
    int cl = (int)((v >> 16) & 255u);
    unsigned int r = v & 0xFFFFu;
    int ph = (int)(r >> 10);
    int p = atomicAdd(&cnt[ph * 256 + cl], 1);
    csr[p] = (((unsigned int)f2bf(dinv[r])) << 16) | r;
  }
}

// --------------------- weight prep: fragment ordering ----------------------
// One kernel for all three fragment sets.
//   [0,8192):     bfW1 from W1 (K=512,N=128)
//   [8192,9216):  bfW2 from W2 (K=128,N=64)
//   [9216,10240): bfH  from W' (K=64,N=128), W'[k][n] = n<64 ? hW1[k][n]
//                 : hW1[64+k][n-64]  (concat head factorization)
__global__ __launch_bounds__(256) void prep_all_kernel(const float* __restrict__ W1,
                                                       const float* __restrict__ W2,
                                                       const float* __restrict__ hW1,
                                                       unsigned short* __restrict__ bfW1,
                                                       unsigned short* __restrict__ bfW2,
                                                       unsigned short* __restrict__ bfH) {
  int idx = blockIdx.x * blockDim.x + threadIdx.x;
  const float* W;
  unsigned short* out;
  int K, N, base, mode;
  if (idx < 8192) {
    W = W1; out = bfW1; K = 512; N = 128; base = 0; mode = 0;
  } else if (idx < 9216) {
    W = W2; out = bfW2; K = 128; N = 64; base = 8192; mode = 0;
  } else if (idx < 10240) {
    W = hW1; out = bfH; K = 64; N = 128; base = 9216; mode = 1;
  } else {
    return;
  }
  int id = idx - base;
  int lane = id & 63;
  int t = id >> 6;
  int KS = K / 32;
  int ks = t % KS;
  int nt = t / KS;
  int n = nt * 16 + (lane & 15);
  int k0 = ks * 32 + (lane >> 4) * 8;
  unsigned short* o = out + (size_t)id * 8;
#pragma unroll
  for (int j = 0; j < 8; ++j) {
    int k = k0 + j;
    float v;
    if (mode == 0)
      v = W[(size_t)k * N + n];
    else
      v = (n < 64) ? W[(size_t)k * 64 + n] : W[(size_t)(64 + k) * 64 + (n - 64)];
    o[j] = f2bf(v);
  }
}

// ------------------------------- MFMA GEMM ---------------------------------
template <int K, int N, bool ABF16, bool OUTF16>
__global__ __launch_bounds__(256) void mfma_gemm_kernel(const void* __restrict__ Ap,
                                                        const unsigned short* __restrict__ Bfrag,
                                                        unsigned short* __restrict__ Cout, int M) {
  constexpr int KS = K / 32;
  constexpr int NT = N / 16;
  const int lane = threadIdx.x & 63;
  const int wid = threadIdx.x >> 6;
  const int quad = lane >> 4;
  const int lc = lane & 15;
  const int mbase = blockIdx.x * 128 + wid * 32;
  if (mbase >= M) return;

  f32x4 acc[2][NT];
#pragma unroll
  for (int mt = 0; mt < 2; ++mt)
#pragma unroll
    for (int nt = 0; nt < NT; ++nt) acc[mt][nt] = (f32x4){0.f, 0.f, 0.f, 0.f};

  int r0 = mbase + lc;
  int r1 = mbase + 16 + lc;
  if (r0 >= M) r0 = M - 1;
  if (r1 >= M) r1 = M - 1;

#pragma unroll
  for (int ks = 0; ks < KS; ++ks) {
    const int k0 = ks * 32 + quad * 8;
    short8x a[2];
    if constexpr (ABF16) {
      const unsigned short* A = (const unsigned short*)Ap;
      a[0] = *(const short8x*)(A + (size_t)r0 * K + k0);
      a[1] = *(const short8x*)(A + (size_t)r1 * K + k0);
    } else {
      const float* A = (const float*)Ap;
      const float4* p0 = (const float4*)(A + (size_t)r0 * K + k0);
      const float4* p1 = (const float4*)(A + (size_t)r1 * K + k0);
      float4 u0 = p0[0], v0 = p0[1];
      float4 u1 = p1[0], v1 = p1[1];
      short8x t0, t1;
      t0[0] = (short)f2bf(u0.x); t0[1] = (short)f2bf(u0.y);
      t0[2] = (short)f2bf(u0.z); t0[3] = (short)f2bf(u0.w);
      t0[4] = (short)f2bf(v0.x); t0[5] = (short)f2bf(v0.y);
      t0[6] = (short)f2bf(v0.z); t0[7] = (short)f2bf(v0.w);
      t1[0] = (short)f2bf(u1.x); t1[1] = (short)f2bf(u1.y);
      t1[2] = (short)f2bf(u1.z); t1[3] = (short)f2bf(u1.w);
      t1[4] = (short)f2bf(v1.x); t1[5] = (short)f2bf(v1.y);
      t1[6] = (short)f2bf(v1.z); t1[7] = (short)f2bf(v1.w);
      a[0] = t0;
      a[1] = t1;
    }
#pragma unroll
    for (int nt = 0; nt < NT; ++nt) {
      short8x b = *(const short8x*)(Bfrag + (((size_t)nt * KS + ks) * 64 + lane) * 8);
      acc[0][nt] = __builtin_amdgcn_mfma_f32_16x16x32_bf16(a[0], b, acc[0][nt], 0, 0, 0);
      acc[1][nt] = __builtin_amdgcn_mfma_f32_16x16x32_bf16(a[1], b, acc[1][nt], 0, 0, 0);
    }
  }

#pragma unroll
  for (int mt = 0; mt < 2; ++mt)
#pragma unroll
    for (int nt = 0; nt < NT; ++nt)
#pragma unroll
      for (int reg = 0; reg < 4; ++reg) {
        int row = mbase + mt * 16 + quad * 4 + reg;
        if (row < M) {
          float v = acc[mt][nt][reg];
          Cout[(size_t)row * N + nt * 16 + lc] = OUTF16 ? f2h(v) : f2bf(v);
        }
      }
}

// ------------------ aggregation (latency-optimized gather) -----------------
// One node per G = F/2 lanes; each lane owns one dword (2 bf16 feats).
// 16-deep edge batching keeps 16 independent gathers in flight per lane.
// CSR segments are src-sorted (round 13), so concurrent nodes' walks gather
// from the same src-quantile window -> L2-resident.
template <int F>
__global__ __launch_bounds__(256) void agg_fast_kernel(
    const unsigned short* __restrict__ xw, const int* __restrict__ offs,
    const unsigned int* __restrict__ csr, const float* __restrict__ dinv,
    const float* __restrict__ bias, const float* __restrict__ gamma,
    const float* __restrict__ beta, const float* __restrict__ mean,
    const float* __restrict__ var, unsigned short* __restrict__ out, int N) {
  constexpr int G = F / 2;
  constexpr int NPB = 256 / G;
  const int li = threadIdx.x % G;
  const int i = blockIdx.x * NPB + threadIdx.x / G;
  if (i >= N) return;
  const unsigned int* xw32 = (const unsigned int*)xw;
  const float di = dinv[i];
  const int s = offs[i], e = offs[i + 1];
  float accL = 0.f, accH = 0.f;
  int t = s;
  for (; t + 16 <= e; t += 16) {
    unsigned int ent[16];
#pragma unroll
    for (int j = 0; j < 16; ++j) ent[j] = __builtin_nontemporal_load(&csr[t + j]);
    unsigned int gv[16];
#pragma unroll
    for (int j = 0; j < 16; ++j) gv[j] = xw32[(size_t)(ent[j] & 0xFFFFu) * G + li];
#pragma unroll
    for (int j = 0; j < 16; ++j) {
      float w = __uint_as_float(ent[j] & 0xFFFF0000u);
      accL += w * __uint_as_float(gv[j] << 16);
      accH += w * __uint_as_float(gv[j] & 0xFFFF0000u);
    }
  }
  for (; t + 4 <= e; t += 4) {
    unsigned int ent[4];
#pragma unroll
    for (int j = 0; j < 4; ++j) ent[j] = __builtin_nontemporal_load(&csr[t + j]);
    unsigned int gv[4];
#pragma unroll
    for (int j = 0; j < 4; ++j) gv[j] = xw32[(size_t)(ent[j] & 0xFFFFu) * G + li];
#pragma unroll
    for (int j = 0; j < 4; ++j) {
      float w = __uint_as_float(ent[j] & 0xFFFF0000u);
      accL += w * __uint_as_float(gv[j] << 16);
      accH += w * __uint_as_float(gv[j] & 0xFFFF0000u);
    }
  }
  for (; t < e; ++t) {
    unsigned int ee = __builtin_nontemporal_load(&csr[t]);
    unsigned int gv = xw32[(size_t)(ee & 0xFFFFu) * G + li];
    float w = __uint_as_float(ee & 0xFFFF0000u);
    accL += w * __uint_as_float(gv << 16);
    accH += w * __uint_as_float(gv & 0xFFFF0000u);
  }
  const int f0 = 2 * li, f1 = f0 + 1;
  unsigned int sv = xw32[(size_t)i * G + li];
  float v0 = di * accL + di * di * __uint_as_float(sv << 16) + bias[f0];
  float v1 = di * accH + di * di * __uint_as_float(sv & 0xFFFF0000u) + bias[f1];
  v0 = (v0 - mean[f0]) * rsqrtf(var[f0] + 1e-5f) * gamma[f0] + beta[f0];
  v1 = (v1 - mean[f1]) * rsqrtf(var[f1] + 1e-5f) * gamma[f1] + beta[f1];
  unsigned int packed =
      (unsigned int)f2bf(fmaxf(v0, 0.f)) | ((unsigned int)f2bf(fmaxf(v1, 0.f)) << 16);
  ((unsigned int*)out)[(size_t)i * G + li] = packed;
}

// ------------------------------- edge head ---------------------------------
// zh[n] = [za(64 f16) || zb(64 f16)], za = z@hW1_top, zb = z@hW1_bot.
// Per edge: logit = relu(za[s]+zb[d]+hb1) . hW2 + hb2.
// Wave layout: lc = edge-in-chunk (16 edges/wave), quad = 16-feature slice.
__global__ __launch_bounds__(256) void head2_kernel(
    const unsigned short* __restrict__ zh, const int* __restrict__ src,
    const int* __restrict__ dst, const float* __restrict__ hb1,
    const float* __restrict__ hw2, const float* __restrict__ hb2,
    float* __restrict__ out, int P) {
  const int lane = threadIdx.x & 63;
  const int lc = lane & 15;
  const int quad = lane >> 4;
  float b1v[16], w2v[16];
#pragma unroll
  for (int t = 0; t < 16; ++t) {
    b1v[t] = hb1[quad * 16 + t];
    w2v[t] = hw2[quad * 16 + t];
  }
  const float bias2 = hb2[0];
  const int nchunks = (P + 15) / 16;
  const int gw = blockIdx.x * 4 + (threadIdx.x >> 6);
  const int nw = gridDim.x * 4;

  for (int ch = gw; ch < nchunks; ch += nw) {
    int p = ch * 16 + lc;
    int pc = p < P ? p : P - 1;
    int s = __builtin_nontemporal_load(&src[pc]);
    int d = __builtin_nontemporal_load(&dst[pc]);
    const half8x* pa = (const half8x*)(zh + (size_t)s * 128 + quad * 16);
    const half8x* pb = (const half8x*)(zh + (size_t)d * 128 + 64 + quad * 16);
    half8x a0 = pa[0], a1 = pa[1];
    half8x b0 = pb[0], b1 = pb[1];
    float acc = 0.f;
#pragma unroll
    for (int t = 0; t < 8; ++t) {
      float hm = fmaxf((float)a0[t] + (float)b0[t] + b1v[t], 0.f);
      acc = fmaf(hm, w2v[t], acc);
    }
#pragma unroll
    for (int t = 0; t < 8; ++t) {
      float hm = fmaxf((float)a1[t] + (float)b1[t] + b1v[8 + t], 0.f);
      acc = fmaf(hm, w2v[8 + t], acc);
    }
    acc += __shfl_xor(acc, 16, 64);
    acc += __shfl_xor(acc, 32, 64);
    if (quad == 0 && p < P) {
      float o = 1.0f / (1.0f + __expf(-(acc + bias2)));
      __builtin_nontemporal_store(o, &out[p]);
    }
  }
}

// ------------------------------- launcher ----------------------------------

extern "C" void kernel_launch(void* const* d_in, const int* in_sizes, int n_in,
                              void* d_out, int out_size, void* d_ws, size_t ws_size,
                              hipStream_t stream) {
  const float* x = (const float*)d_in[0];
  const int* ei = (const int*)d_in[1];
  const int* src = (const int*)d_in[2];
  const int* dst = (const int*)d_in[3];
  const float* W1 = (const float*)d_in[4];
  const float* b1 = (const float*)d_in[5];
  const float* g1 = (const float*)d_in[6];
  const float* be1 = (const float*)d_in[7];
  const float* mu1 = (const float*)d_in[8];
  const float* va1 = (const float*)d_in[9];
  const float* W2 = (const float*)d_in[10];
  const float* b2 = (const float*)d_in[11];
  const float* g2 = (const float*)d_in[12];
  const float* be2 = (const float*)d_in[13];
  const float* mu2 = (const float*)d_in[14];
  const float* va2 = (const float*)d_in[15];
  const float* hW1 = (const float*)d_in[16];
  const float* hb1 = (const float*)d_in[17];
  const float* hW2 = (const float*)d_in[18];
  const float* hb2 = (const float*)d_in[19];
  float* out = (float*)d_out;

  const int N = in_sizes[0] / 512;
  const int E = in_sizes[1] / 2;
  const int P = in_sizes[2];
  const int* row = ei;
  const int* col = ei + E;
  const int NBK = (N + 255) / 256;    // buckets (256 nodes each), <=256
  const int NAB = (E + 4095) / 4096;  // binA blocks

  char* wp = (char*)d_ws;
  auto alloc = [&](size_t bytes) {
    char* p = wp;
    wp += (bytes + 255) & ~(size_t)255;
    return p;
  };
  unsigned short* xw1 = (unsigned short*)alloc((size_t)N * 128 * 2);
  unsigned short* h = (unsigned short*)alloc((size_t)N * 128 * 2);
  unsigned short* xw2 = (unsigned short*)alloc((size_t)N * 64 * 2);
  unsigned short* z = (unsigned short*)alloc((size_t)N * 64 * 2);
  unsigned short* zh = (unsigned short*)alloc((size_t)N * 128 * 2);  // f16 [za||zb]
  float* dinv = (float*)alloc((size_t)N * 4);
  int* offs = (int*)alloc((size_t)(N + 1) * 4);
  unsigned int* csr = (unsigned int*)alloc((size_t)E * 4);
  unsigned int* staging = (unsigned int*)alloc((size_t)E * 4);
  int* bucket_count = (int*)alloc((size_t)NBK * 4);
  int* bucket_start = (int*)alloc((size_t)(NBK + 1) * 4);
  int* bcur = (int*)alloc((size_t)NBK * 4);
  unsigned short* bfW1 = (unsigned short*)alloc(512 * 128 * 2);
  unsigned short* bfW2 = (unsigned short*)alloc(128 * 64 * 2);
  unsigned short* bfH = (unsigned short*)alloc(128 * 64 * 2);
  (void)ws_size;
  (void)n_in;
  (void)out_size;

  // --- graph structure (no per-node global atomics anywhere) ---
  hipLaunchKernelGGL(zero_int_kernel, dim3((NBK + 255) / 256), dim3(256), 0, stream, bucket_count,
                     NBK);
  hipLaunchKernelGGL(binA_hist_kernel, dim3(NAB), dim3(256), 0, stream, col, bucket_count, E, NBK);
  hipLaunchKernelGGL(scan_buckets_kernel, dim3(1), dim3(256), 0, stream, bucket_count,
                     bucket_start, bcur, offs + N, NBK, E);
  hipLaunchKernelGGL(binA_scatter_kernel, dim3(NAB), dim3(256), 0, stream, row, col, bcur, staging,
                     E, NBK);
  hipLaunchKernelGGL(binB1_kernel, dim3(NBK), dim3(256), 0, stream, staging, bucket_start, offs,
                     dinv, N);
  hipLaunchKernelGGL(binB2_kernel, dim3(NBK), dim3(256), 0, stream, staging, bucket_start, dinv,
                     csr);

  // --- weight fragment prep (single kernel) ---
  hipLaunchKernelGGL(prep_all_kernel, dim3(40), dim3(256), 0, stream, W1, W2, hW1, bfW1, bfW2,
                     bfH);

  // --- layer 1 ---
  hipLaunchKernelGGL((mfma_gemm_kernel<512, 128, false, false>), dim3((N + 127) / 128), dim3(256),
                     0, stream, x, bfW1, xw1, N);
  hipLaunchKernelGGL((agg_fast_kernel<128>), dim3((N + 3) / 4), dim3(256), 0, stream, xw1, offs,
                     csr, dinv, b1, g1, be1, mu1, va1, h, N);

  // --- layer 2 ---
  hipLaunchKernelGGL((mfma_gemm_kernel<128, 64, true, false>), dim3((N + 127) / 128), dim3(256), 0,
                     stream, h, bfW2, xw2, N);
  hipLaunchKernelGGL((agg_fast_kernel<64>), dim3((N + 7) / 8), dim3(256), 0, stream, xw2, offs,
                     csr, dinv, b2, g2, be2, mu2, va2, z, N);

  // --- edge head: node-side GEMM then per-edge add/relu/dot ---
  hipLaunchKernelGGL((mfma_gemm_kernel<64, 128, true, true>), dim3((N + 127) / 128), dim3(256), 0,
                     stream, z, bfH, zh, N);
  hipLaunchKernelGGL(head2_kernel, dim3(2048), dim3(256), 0, stream, zh, src, dst, hb1, hW2, hb2,
                     out, P);
}

// Round 6
// 400.283 us; speedup vs baseline: 6.1624x; 1.0248x over previous
//
#include <hip/hip_runtime.h>
#include <math.h>

// ---------------------------------------------------------------------------
// GCN link predictor on MI355X, round 14.
// Round-13 post-mortem: src-sorted CSR changed FETCH_SIZE by 0% (159.8->159.3
// MB). Cause: avg degree = 32 -- per-node sorting cannot align concurrent
// nodes' gathers when each node touches 32 uniform-random rows. Locality
// program abandoned; agg is co-limited by instruction issue (VALUBusy 44%)
// and the L2-miss path (2.9 TB/s). Round 14 attacks the issue side:
//   1. agg gathers 8B/lane (dwordx2): G=RD/2 lanes/node -> gather insts and
//      addr-calc per edge halved; same bytes; accumulation order identical.
//   2. float2 accumulators via __builtin_elementwise_fma -> v_pk_fma_f32
//      (half the MAC instructions).
//   3. binB1/binB2 reverted to round-10 simple versions (r13 sorter was
//      +7us total for zero FETCH benefit).
// Falsification test: if agg1 stays ~60us with FETCH ~160MB, it is purely
// miss-path-bound and at its floor.
// Kept: factored edge head, prep_all, bucketed build, bf16 MFMA GEMMs.
// ---------------------------------------------------------------------------

typedef __attribute__((ext_vector_type(8))) short short8x;
typedef __attribute__((ext_vector_type(8))) _Float16 half8x;
typedef __attribute__((ext_vector_type(4))) float f32x4;
typedef __attribute__((ext_vector_type(2))) unsigned int uint2x;
typedef __attribute__((ext_vector_type(2))) float float2x;

__device__ __forceinline__ unsigned short f2bf(float f) {
  unsigned int u = __float_as_uint(f);
  unsigned int r = u + 0x7FFFu + ((u >> 16) & 1u);  // RNE
  return (unsigned short)(r >> 16);
}
__device__ __forceinline__ unsigned short f2h(float f) {
  union { _Float16 h; unsigned short u; } cv;
  cv.h = (_Float16)f;  // v_cvt_f16_f32, RNE
  return cv.u;
}

// ------------------------------ graph build --------------------------------

__global__ void zero_int_kernel(int* __restrict__ p, int n) {
  int i = blockIdx.x * blockDim.x + threadIdx.x;
  if (i < n) p[i] = 0;
}

// Per-block LDS histogram over buckets (col>>8); one global atomic per
// (block,bucket). 4096 edges/block.
__global__ __launch_bounds__(256) void binA_hist_kernel(const int* __restrict__ col,
                                                        int* __restrict__ bucket_count, int E,
                                                        int NBK) {
  __shared__ int hist[256];
  const int tid = threadIdx.x;
  hist[tid] = 0;
  __syncthreads();
  const int base = blockIdx.x * 4096;
#pragma unroll
  for (int j = 0; j < 16; ++j) {
    int i = base + j * 256 + tid;
    if (i < E) atomicAdd(&hist[((unsigned int)col[i]) >> 8], 1);
  }
  __syncthreads();
  if (tid < NBK) {
    int h = hist[tid];
    if (h) atomicAdd(&bucket_count[tid], h);
  }
}

// Single block: exclusive scan of NBK (<=256) bucket counts.
__global__ __launch_bounds__(256) void scan_buckets_kernel(const int* __restrict__ bucket_count,
                                                           int* __restrict__ bucket_start,
                                                           int* __restrict__ bcur,
                                                           int* __restrict__ offs_n, int NBK,
                                                           int E) {
  __shared__ int ws[4];
  const int tid = threadIdx.x;
  const int lane = tid & 63;
  const int wid = tid >> 6;
  int v = (tid < NBK) ? bucket_count[tid] : 0;
  int incl = v;
#pragma unroll
  for (int d = 1; d < 64; d <<= 1) {
    int t = __shfl_up(incl, d, 64);
    if (lane >= d) incl += t;
  }
  if (lane == 63) ws[wid] = incl;
  __syncthreads();
  int woff = 0;
#pragma unroll
  for (int w = 0; w < 4; ++w)
    if (w < wid) woff += ws[w];
  int excl = woff + incl - v;
  if (tid < NBK) {
    bucket_start[tid] = excl;
    bcur[tid] = excl;
  }
  if (tid == 0) {
    bucket_start[NBK] = E;
    *offs_n = E;
  }
}

// binA_scatter: 4096 edges/block; LDS hist -> one global atomicAdd per
// (block,bucket) reserve -> LDS-cursor scatter of packed (col<<16|row).
__global__ __launch_bounds__(256) void binA_scatter_kernel(const int* __restrict__ row,
                                                           const int* __restrict__ col,
                                                           int* __restrict__ bcur,
                                                           unsigned int* __restrict__ staging,
                                                           int E, int NBK) {
  __shared__ int hist[256];
  const int tid = threadIdx.x;
  hist[tid] = 0;
  __syncthreads();
  const int base = blockIdx.x * 4096;
  unsigned int payload[16];
  int bk[16];
#pragma unroll
  for (int j = 0; j < 16; ++j) {
    int i = base + j * 256 + tid;
    if (i < E) {
      unsigned int c = (unsigned int)__builtin_nontemporal_load(&col[i]);
      unsigned int r = (unsigned int)__builtin_nontemporal_load(&row[i]);
      payload[j] = (c << 16) | r;
      bk[j] = (int)(c >> 8);
      atomicAdd(&hist[bk[j]], 1);
    } else {
      bk[j] = -1;
    }
  }
  __syncthreads();
  if (tid < NBK) {
    int h = hist[tid];
    hist[tid] = h ? atomicAdd(&bcur[tid], h) : 0;
  }
  __syncthreads();
#pragma unroll
  for (int j = 0; j < 16; ++j) {
    if (bk[j] >= 0) {
      int p = atomicAdd(&hist[bk[j]], 1);
      staging[p] = payload[j];
    }
  }
}

// binB1: one block per 256-node bucket. LDS node-histogram of the bucket's
// staging segment -> LDS scan -> writes offs[node] and dinv[node].
__global__ __launch_bounds__(256) void binB1_kernel(const unsigned int* __restrict__ staging,
                                                    const int* __restrict__ bucket_start,
                                                    int* __restrict__ offs,
                                                    float* __restrict__ dinv, int N) {
  __shared__ int cnt[256];
  __shared__ int ws[4];
  const int b = blockIdx.x;
  const int n0 = b * 256;
  const int tid = threadIdx.x;
  cnt[tid] = 0;
  __syncthreads();
  const int s = bucket_start[b];
  const int e = bucket_start[b + 1];
  for (int t = s + tid; t < e; t += 256) {
    atomicAdd(&cnt[(staging[t] >> 16) & 255u], 1);
  }
  __syncthreads();
  const int deg = cnt[tid];
  const int lane = tid & 63;
  const int wid = tid >> 6;
  int incl = deg;
#pragma unroll
  for (int d = 1; d < 64; d <<= 1) {
    int t = __shfl_up(incl, d, 64);
    if (lane >= d) incl += t;
  }
  if (lane == 63) ws[wid] = incl;
  __syncthreads();
  int woff = 0;
#pragma unroll
  for (int w = 0; w < 4; ++w)
    if (w < wid) woff += ws[w];
  const int excl = woff + incl - deg;
  const int node = n0 + tid;
  if (node < N) {
    offs[node] = s + excl;
    dinv[node] = rsqrtf((float)deg + 1.0f);
  }
}

// binB2: fine scatter into CSR with packed bf16 dinv.
__global__ __launch_bounds__(512) void binB2_kernel(const unsigned int* __restrict__ staging,
                                                    const int* __restrict__ offs,
                                                    const int* __restrict__ bucket_start,
                                                    const float* __restrict__ dinv,
                                                    unsigned int* __restrict__ csr, int N) {
  __shared__ int cur[256];
  const int b = blockIdx.x;
  const int n0 = b * 256;
  const int tid = threadIdx.x;
  if (tid < 256 && n0 + tid < N) cur[tid] = offs[n0 + tid];
  __syncthreads();
  const int s = bucket_start[b];
  const int e = bucket_start[b + 1];
  for (int t = s + tid; t < e; t += 512) {
    unsigned int v = __builtin_nontemporal_load(&staging[t]);
    int cl = (int)((v >> 16) & 255u);
    unsigned int r = v & 0xFFFFu;
    unsigned int wd = f2bf(dinv[r]);
    int p = atomicAdd(&cur[cl], 1);
    csr[p] = (wd << 16) | r;
  }
}

// --------------------- weight prep: fragment ordering ----------------------
// One kernel for all three fragment sets.
//   [0,8192):     bfW1 from W1 (K=512,N=128)
//   [8192,9216):  bfW2 from W2 (K=128,N=64)
//   [9216,10240): bfH  from W' (K=64,N=128), W'[k][n] = n<64 ? hW1[k][n]
//                 : hW1[64+k][n-64]  (concat head factorization)
__global__ __launch_bounds__(256) void prep_all_kernel(const float* __restrict__ W1,
                                                       const float* __restrict__ W2,
                                                       const float* __restrict__ hW1,
                                                       unsigned short* __restrict__ bfW1,
                                                       unsigned short* __restrict__ bfW2,
                                                       unsigned short* __restrict__ bfH) {
  int idx = blockIdx.x * blockDim.x + threadIdx.x;
  const float* W;
  unsigned short* out;
  int K, N, base, mode;
  if (idx < 8192) {
    W = W1; out = bfW1; K = 512; N = 128; base = 0; mode = 0;
  } else if (idx < 9216) {
    W = W2; out = bfW2; K = 128; N = 64; base = 8192; mode = 0;
  } else if (idx < 10240) {
    W = hW1; out = bfH; K = 64; N = 128; base = 9216; mode = 1;
  } else {
    return;
  }
  int id = idx - base;
  int lane = id & 63;
  int t = id >> 6;
  int KS = K / 32;
  int ks = t % KS;
  int nt = t / KS;
  int n = nt * 16 + (lane & 15);
  int k0 = ks * 32 + (lane >> 4) * 8;
  unsigned short* o = out + (size_t)id * 8;
#pragma unroll
  for (int j = 0; j < 8; ++j) {
    int k = k0 + j;
    float v;
    if (mode == 0)
      v = W[(size_t)k * N + n];
    else
      v = (n < 64) ? W[(size_t)k * 64 + n] : W[(size_t)(64 + k) * 64 + (n - 64)];
    o[j] = f2bf(v);
  }
}

// ------------------------------- MFMA GEMM ---------------------------------
template <int K, int N, bool ABF16, bool OUTF16>
__global__ __launch_bounds__(256) void mfma_gemm_kernel(const void* __restrict__ Ap,
                                                        const unsigned short* __restrict__ Bfrag,
                                                        unsigned short* __restrict__ Cout, int M) {
  constexpr int KS = K / 32;
  constexpr int NT = N / 16;
  const int lane = threadIdx.x & 63;
  const int wid = threadIdx.x >> 6;
  const int quad = lane >> 4;
  const int lc = lane & 15;
  const int mbase = blockIdx.x * 128 + wid * 32;
  if (mbase >= M) return;

  f32x4 acc[2][NT];
#pragma unroll
  for (int mt = 0; mt < 2; ++mt)
#pragma unroll
    for (int nt = 0; nt < NT; ++nt) acc[mt][nt] = (f32x4){0.f, 0.f, 0.f, 0.f};

  int r0 = mbase + lc;
  int r1 = mbase + 16 + lc;
  if (r0 >= M) r0 = M - 1;
  if (r1 >= M) r1 = M - 1;

#pragma unroll
  for (int ks = 0; ks < KS; ++ks) {
    const int k0 = ks * 32 + quad * 8;
    short8x a[2];
    if constexpr (ABF16) {
      const unsigned short* A = (const unsigned short*)Ap;
      a[0] = *(const short8x*)(A + (size_t)r0 * K + k0);
      a[1] = *(const short8x*)(A + (size_t)r1 * K + k0);
    } else {
      const float* A = (const float*)Ap;
      const float4* p0 = (const float4*)(A + (size_t)r0 * K + k0);
      const float4* p1 = (const float4*)(A + (size_t)r1 * K + k0);
      float4 u0 = p0[0], v0 = p0[1];
      float4 u1 = p1[0], v1 = p1[1];
      short8x t0, t1;
      t0[0] = (short)f2bf(u0.x); t0[1] = (short)f2bf(u0.y);
      t0[2] = (short)f2bf(u0.z); t0[3] = (short)f2bf(u0.w);
      t0[4] = (short)f2bf(v0.x); t0[5] = (short)f2bf(v0.y);
      t0[6] = (short)f2bf(v0.z); t0[7] = (short)f2bf(v0.w);
      t1[0] = (short)f2bf(u1.x); t1[1] = (short)f2bf(u1.y);
      t1[2] = (short)f2bf(u1.z); t1[3] = (short)f2bf(u1.w);
      t1[4] = (short)f2bf(v1.x); t1[5] = (short)f2bf(v1.y);
      t1[6] = (short)f2bf(v1.z); t1[7] = (short)f2bf(v1.w);
      a[0] = t0;
      a[1] = t1;
    }
#pragma unroll
    for (int nt = 0; nt < NT; ++nt) {
      short8x b = *(const short8x*)(Bfrag + (((size_t)nt * KS + ks) * 64 + lane) * 8);
      acc[0][nt] = __builtin_amdgcn_mfma_f32_16x16x32_bf16(a[0], b, acc[0][nt], 0, 0, 0);
      acc[1][nt] = __builtin_amdgcn_mfma_f32_16x16x32_bf16(a[1], b, acc[1][nt], 0, 0, 0);
    }
  }

#pragma unroll
  for (int mt = 0; mt < 2; ++mt)
#pragma unroll
    for (int nt = 0; nt < NT; ++nt)
#pragma unroll
      for (int reg = 0; reg < 4; ++reg) {
        int row = mbase + mt * 16 + quad * 4 + reg;
        if (row < M) {
          float v = acc[mt][nt][reg];
          Cout[(size_t)row * N + nt * 16 + lc] = OUTF16 ? f2h(v) : f2bf(v);
        }
      }
}

// ------------------ aggregation (8B-lane gather, packed FMA) ---------------
// RD = dwords per feature row. G = RD/2 lanes per node; each lane owns one
// dwordx2 (4 bf16 feats). 16-deep edge batching; per-feature accumulation
// order identical to previous rounds (bit-identical modulo fma).
template <int RD>
__global__ __launch_bounds__(256) void agg_fast_kernel(
    const unsigned short* __restrict__ xw, const int* __restrict__ offs,
    const unsigned int* __restrict__ csr, const float* __restrict__ dinv,
    const float* __restrict__ bias, const float* __restrict__ gamma,
    const float* __restrict__ beta, const float* __restrict__ mean,
    const float* __restrict__ var, unsigned short* __restrict__ out, int N) {
  constexpr int G = RD / 2;  // lanes per node (uint2x each)
  constexpr int NPB = 256 / G;
  const int li = threadIdx.x % G;
  const int i = blockIdx.x * NPB + threadIdx.x / G;
  if (i >= N) return;
  const uint2x* xw64 = (const uint2x*)xw;  // row stride = G uint2x
  const float di = dinv[i];
  const int s = offs[i], e = offs[i + 1];
  float2x acc0 = {0.f, 0.f};  // feats (4li, 4li+1)
  float2x acc1 = {0.f, 0.f};  // feats (4li+2, 4li+3)
  int t = s;
  for (; t + 16 <= e; t += 16) {
    unsigned int ent[16];
#pragma unroll
    for (int j = 0; j < 16; ++j) ent[j] = __builtin_nontemporal_load(&csr[t + j]);
    uint2x gv[16];
#pragma unroll
    for (int j = 0; j < 16; ++j) gv[j] = xw64[(size_t)(ent[j] & 0xFFFFu) * G + li];
#pragma unroll
    for (int j = 0; j < 16; ++j) {
      float w = __uint_as_float(ent[j] & 0xFFFF0000u);
      float2x wv = {w, w};
      float2x x0 = {__uint_as_float(gv[j].x << 16), __uint_as_float(gv[j].x & 0xFFFF0000u)};
      float2x x1 = {__uint_as_float(gv[j].y << 16), __uint_as_float(gv[j].y & 0xFFFF0000u)};
      acc0 = __builtin_elementwise_fma(wv, x0, acc0);
      acc1 = __builtin_elementwise_fma(wv, x1, acc1);
    }
  }
  for (; t + 4 <= e; t += 4) {
    unsigned int ent[4];
#pragma unroll
    for (int j = 0; j < 4; ++j) ent[j] = __builtin_nontemporal_load(&csr[t + j]);
    uint2x gv[4];
#pragma unroll
    for (int j = 0; j < 4; ++j) gv[j] = xw64[(size_t)(ent[j] & 0xFFFFu) * G + li];
#pragma unroll
    for (int j = 0; j < 4; ++j) {
      float w = __uint_as_float(ent[j] & 0xFFFF0000u);
      float2x wv = {w, w};
      float2x x0 = {__uint_as_float(gv[j].x << 16), __uint_as_float(gv[j].x & 0xFFFF0000u)};
      float2x x1 = {__uint_as_float(gv[j].y << 16), __uint_as_float(gv[j].y & 0xFFFF0000u)};
      acc0 = __builtin_elementwise_fma(wv, x0, acc0);
      acc1 = __builtin_elementwise_fma(wv, x1, acc1);
    }
  }
  for (; t < e; ++t) {
    unsigned int ee = __builtin_nontemporal_load(&csr[t]);
    uint2x gv = xw64[(size_t)(ee & 0xFFFFu) * G + li];
    float w = __uint_as_float(ee & 0xFFFF0000u);
    float2x wv = {w, w};
    float2x x0 = {__uint_as_float(gv.x << 16), __uint_as_float(gv.x & 0xFFFF0000u)};
    float2x x1 = {__uint_as_float(gv.y << 16), __uint_as_float(gv.y & 0xFFFF0000u)};
    acc0 = __builtin_elementwise_fma(wv, x0, acc0);
    acc1 = __builtin_elementwise_fma(wv, x1, acc1);
  }
  const int f0 = 4 * li;
  uint2x sv = xw64[(size_t)i * G + li];
  float sl0 = __uint_as_float(sv.x << 16), sh0 = __uint_as_float(sv.x & 0xFFFF0000u);
  float sl1 = __uint_as_float(sv.y << 16), sh1 = __uint_as_float(sv.y & 0xFFFF0000u);
  const float dd = di * di;
  float v0 = di * acc0.x + dd * sl0 + bias[f0 + 0];
  float v1 = di * acc0.y + dd * sh0 + bias[f0 + 1];
  float v2 = di * acc1.x + dd * sl1 + bias[f0 + 2];
  float v3 = di * acc1.y + dd * sh1 + bias[f0 + 3];
  v0 = (v0 - mean[f0 + 0]) * rsqrtf(var[f0 + 0] + 1e-5f) * gamma[f0 + 0] + beta[f0 + 0];
  v1 = (v1 - mean[f0 + 1]) * rsqrtf(var[f0 + 1] + 1e-5f) * gamma[f0 + 1] + beta[f0 + 1];
  v2 = (v2 - mean[f0 + 2]) * rsqrtf(var[f0 + 2] + 1e-5f) * gamma[f0 + 2] + beta[f0 + 2];
  v3 = (v3 - mean[f0 + 3]) * rsqrtf(var[f0 + 3] + 1e-5f) * gamma[f0 + 3] + beta[f0 + 3];
  uint2x packed;
  packed.x = (unsigned int)f2bf(fmaxf(v0, 0.f)) | ((unsigned int)f2bf(fmaxf(v1, 0.f)) << 16);
  packed.y = (unsigned int)f2bf(fmaxf(v2, 0.f)) | ((unsigned int)f2bf(fmaxf(v3, 0.f)) << 16);
  ((uint2x*)out)[(size_t)i * G + li] = packed;
}

// ------------------------------- edge head ---------------------------------
// zh[n] = [za(64 f16) || zb(64 f16)], za = z@hW1_top, zb = z@hW1_bot.
// Per edge: logit = relu(za[s]+zb[d]+hb1) . hW2 + hb2.
// Wave layout: lc = edge-in-chunk (16 edges/wave), quad = 16-feature slice.
__global__ __launch_bounds__(256) void head2_kernel(
    const unsigned short* __restrict__ zh, const int* __restrict__ src,
    const int* __restrict__ dst, const float* __restrict__ hb1,
    const float* __restrict__ hw2, const float* __restrict__ hb2,
    float* __restrict__ out, int P) {
  const int lane = threadIdx.x & 63;
  const int lc = lane & 15;
  const int quad = lane >> 4;
  float b1v[16], w2v[16];
#pragma unroll
  for (int t = 0; t < 16; ++t) {
    b1v[t] = hb1[quad * 16 + t];
    w2v[t] = hw2[quad * 16 + t];
  }
  const float bias2 = hb2[0];
  const int nchunks = (P + 15) / 16;
  const int gw = blockIdx.x * 4 + (threadIdx.x >> 6);
  const int nw = gridDim.x * 4;

  for (int ch = gw; ch < nchunks; ch += nw) {
    int p = ch * 16 + lc;
    int pc = p < P ? p : P - 1;
    int s = __builtin_nontemporal_load(&src[pc]);
    int d = __builtin_nontemporal_load(&dst[pc]);
    const half8x* pa = (const half8x*)(zh + (size_t)s * 128 + quad * 16);
    const half8x* pb = (const half8x*)(zh + (size_t)d * 128 + 64 + quad * 16);
    half8x a0 = pa[0], a1 = pa[1];
    half8x b0 = pb[0], b1 = pb[1];
    float acc = 0.f;
#pragma unroll
    for (int t = 0; t < 8; ++t) {
      float hm = fmaxf((float)a0[t] + (float)b0[t] + b1v[t], 0.f);
      acc = fmaf(hm, w2v[t], acc);
    }
#pragma unroll
    for (int t = 0; t < 8; ++t) {
      float hm = fmaxf((float)a1[t] + (float)b1[t] + b1v[8 + t], 0.f);
      acc = fmaf(hm, w2v[8 + t], acc);
    }
    acc += __shfl_xor(acc, 16, 64);
    acc += __shfl_xor(acc, 32, 64);
    if (quad == 0 && p < P) {
      float o = 1.0f / (1.0f + __expf(-(acc + bias2)));
      __builtin_nontemporal_store(o, &out[p]);
    }
  }
}

// ------------------------------- launcher ----------------------------------

extern "C" void kernel_launch(void* const* d_in, const int* in_sizes, int n_in,
                              void* d_out, int out_size, void* d_ws, size_t ws_size,
                              hipStream_t stream) {
  const float* x = (const float*)d_in[0];
  const int* ei = (const int*)d_in[1];
  const int* src = (const int*)d_in[2];
  const int* dst = (const int*)d_in[3];
  const float* W1 = (const float*)d_in[4];
  const float* b1 = (const float*)d_in[5];
  const float* g1 = (const float*)d_in[6];
  const float* be1 = (const float*)d_in[7];
  const float* mu1 = (const float*)d_in[8];
  const float* va1 = (const float*)d_in[9];
  const float* W2 = (const float*)d_in[10];
  const float* b2 = (const float*)d_in[11];
  const float* g2 = (const float*)d_in[12];
  const float* be2 = (const float*)d_in[13];
  const float* mu2 = (const float*)d_in[14];
  const float* va2 = (const float*)d_in[15];
  const float* hW1 = (const float*)d_in[16];
  const float* hb1 = (const float*)d_in[17];
  const float* hW2 = (const float*)d_in[18];
  const float* hb2 = (const float*)d_in[19];
  float* out = (float*)d_out;

  const int N = in_sizes[0] / 512;
  const int E = in_sizes[1] / 2;
  const int P = in_sizes[2];
  const int* row = ei;
  const int* col = ei + E;
  const int NBK = (N + 255) / 256;    // buckets (256 nodes each), <=256
  const int NAB = (E + 4095) / 4096;  // binA blocks

  char* wp = (char*)d_ws;
  auto alloc = [&](size_t bytes) {
    char* p = wp;
    wp += (bytes + 255) & ~(size_t)255;
    return p;
  };
  unsigned short* xw1 = (unsigned short*)alloc((size_t)N * 128 * 2);
  unsigned short* h = (unsigned short*)alloc((size_t)N * 128 * 2);
  unsigned short* xw2 = (unsigned short*)alloc((size_t)N * 64 * 2);
  unsigned short* z = (unsigned short*)alloc((size_t)N * 64 * 2);
  unsigned short* zh = (unsigned short*)alloc((size_t)N * 128 * 2);  // f16 [za||zb]
  float* dinv = (float*)alloc((size_t)N * 4);
  int* offs = (int*)alloc((size_t)(N + 1) * 4);
  unsigned int* csr = (unsigned int*)alloc((size_t)E * 4);
  unsigned int* staging = (unsigned int*)alloc((size_t)E * 4);
  int* bucket_count = (int*)alloc((size_t)NBK * 4);
  int* bucket_start = (int*)alloc((size_t)(NBK + 1) * 4);
  int* bcur = (int*)alloc((size_t)NBK * 4);
  unsigned short* bfW1 = (unsigned short*)alloc(512 * 128 * 2);
  unsigned short* bfW2 = (unsigned short*)alloc(128 * 64 * 2);
  unsigned short* bfH = (unsigned short*)alloc(128 * 64 * 2);
  (void)ws_size;
  (void)n_in;
  (void)out_size;

  // --- graph structure (no per-node global atomics anywhere) ---
  hipLaunchKernelGGL(zero_int_kernel, dim3((NBK + 255) / 256), dim3(256), 0, stream, bucket_count,
                     NBK);
  hipLaunchKernelGGL(binA_hist_kernel, dim3(NAB), dim3(256), 0, stream, col, bucket_count, E, NBK);
  hipLaunchKernelGGL(scan_buckets_kernel, dim3(1), dim3(256), 0, stream, bucket_count,
                     bucket_start, bcur, offs + N, NBK, E);
  hipLaunchKernelGGL(binA_scatter_kernel, dim3(NAB), dim3(256), 0, stream, row, col, bcur, staging,
                     E, NBK);
  hipLaunchKernelGGL(binB1_kernel, dim3(NBK), dim3(256), 0, stream, staging, bucket_start, offs,
                     dinv, N);
  hipLaunchKernelGGL(binB2_kernel, dim3(NBK), dim3(512), 0, stream, staging, offs, bucket_start,
                     dinv, csr, N);

  // --- weight fragment prep (single kernel) ---
  hipLaunchKernelGGL(prep_all_kernel, dim3(40), dim3(256), 0, stream, W1, W2, hW1, bfW1, bfW2,
                     bfH);

  // --- layer 1 ---
  hipLaunchKernelGGL((mfma_gemm_kernel<512, 128, false, false>), dim3((N + 127) / 128), dim3(256),
                     0, stream, x, bfW1, xw1, N);
  hipLaunchKernelGGL((agg_fast_kernel<64>), dim3((N + 7) / 8), dim3(256), 0, stream, xw1, offs,
                     csr, dinv, b1, g1, be1, mu1, va1, h, N);

  // --- layer 2 ---
  hipLaunchKernelGGL((mfma_gemm_kernel<128, 64, true, false>), dim3((N + 127) / 128), dim3(256), 0,
                     stream, h, bfW2, xw2, N);
  hipLaunchKernelGGL((agg_fast_kernel<32>), dim3((N + 15) / 16), dim3(256), 0, stream, xw2, offs,
                     csr, dinv, b2, g2, be2, mu2, va2, z, N);

  // --- edge head: node-side GEMM then per-edge add/relu/dot ---
  hipLaunchKernelGGL((mfma_gemm_kernel<64, 128, true, true>), dim3((N + 127) / 128), dim3(256), 0,
                     stream, z, bfH, zh, N);
  hipLaunchKernelGGL(head2_kernel, dim3(2048), dim3(256), 0, stream, zh, src, dst, hb1, hW2, hb2,
                     out, P);
}

// Round 7
// 395.426 us; speedup vs baseline: 6.2381x; 1.0123x over previous
//
#include <hip/hip_runtime.h>
#include <math.h>

// ---------------------------------------------------------------------------
// GCN link predictor on MI355X, round 15.
// Round-14 post-mortem: halving agg's issue work changed nothing (60.2us,
// FETCH 160MB, VALUBusy 44->36%) -> agg1 is miss-path-bound at ~2.9TB/s,
// near its cache-geometry floor (compulsory ~102MB vs 160MB). agg frozen.
// Round 15 attacks the serial pipeline and the latency-bound edge head:
//   1. GEMM1 fused into binA_scatter's launch (block-range dispatch):
//      MFMA/HBM-stream work overlaps LDS-atomic scatter (different pipes).
//   2. prep_all fused into binA_hist's launch (+40 blocks). 13->11 launches.
//   3. head2: 2-chunk unroll (8 gathers in flight per lane, was 4),
//      grid 2048->4096.
// Kept: r14 agg (8B-lane, packed FMA), factored edge head, bucketed build,
// bf16 MFMA GEMMs.
// ---------------------------------------------------------------------------

typedef __attribute__((ext_vector_type(8))) short short8x;
typedef __attribute__((ext_vector_type(8))) _Float16 half8x;
typedef __attribute__((ext_vector_type(4))) float f32x4;
typedef __attribute__((ext_vector_type(2))) unsigned int uint2x;
typedef __attribute__((ext_vector_type(2))) float float2x;

__device__ __forceinline__ unsigned short f2bf(float f) {
  unsigned int u = __float_as_uint(f);
  unsigned int r = u + 0x7FFFu + ((u >> 16) & 1u);  // RNE
  return (unsigned short)(r >> 16);
}
__device__ __forceinline__ unsigned short f2h(float f) {
  union { _Float16 h; unsigned short u; } cv;
  cv.h = (_Float16)f;  // v_cvt_f16_f32, RNE
  return cv.u;
}

// ------------------------------ graph build --------------------------------

__global__ void zero_int_kernel(int* __restrict__ p, int n) {
  int i = blockIdx.x * blockDim.x + threadIdx.x;
  if (i < n) p[i] = 0;
}

// --------------------- weight prep body (device) ---------------------------
__device__ __forceinline__ void prep_body(int idx, const float* __restrict__ W1,
                                          const float* __restrict__ W2,
                                          const float* __restrict__ hW1,
                                          unsigned short* __restrict__ bfW1,
                                          unsigned short* __restrict__ bfW2,
                                          unsigned short* __restrict__ bfH) {
  const float* W;
  unsigned short* out;
  int K, N, base, mode;
  if (idx < 8192) {
    W = W1; out = bfW1; K = 512; N = 128; base = 0; mode = 0;
  } else if (idx < 9216) {
    W = W2; out = bfW2; K = 128; N = 64; base = 8192; mode = 0;
  } else if (idx < 10240) {
    W = hW1; out = bfH; K = 64; N = 128; base = 9216; mode = 1;
  } else {
    return;
  }
  int id = idx - base;
  int lane = id & 63;
  int t = id >> 6;
  int KS = K / 32;
  int ks = t % KS;
  int nt = t / KS;
  int n = nt * 16 + (lane & 15);
  int k0 = ks * 32 + (lane >> 4) * 8;
  unsigned short* o = out + (size_t)id * 8;
#pragma unroll
  for (int j = 0; j < 8; ++j) {
    int k = k0 + j;
    float v;
    if (mode == 0)
      v = W[(size_t)k * N + n];
    else
      v = (n < 64) ? W[(size_t)k * 64 + n] : W[(size_t)(64 + k) * 64 + (n - 64)];
    o[j] = f2bf(v);
  }
}

// binA_hist (+fused weight prep in extra blocks): per-block LDS histogram
// over buckets (col>>8); one global atomic per (block,bucket).
__global__ __launch_bounds__(256) void hist_prep_kernel(
    const int* __restrict__ col, int* __restrict__ bucket_count, int E, int NBK, int NAB,
    const float* __restrict__ W1, const float* __restrict__ W2, const float* __restrict__ hW1,
    unsigned short* __restrict__ bfW1, unsigned short* __restrict__ bfW2,
    unsigned short* __restrict__ bfH) {
  __shared__ int hist[256];
  if ((int)blockIdx.x >= NAB) {
    prep_body(((int)blockIdx.x - NAB) * 256 + threadIdx.x, W1, W2, hW1, bfW1, bfW2, bfH);
    return;
  }
  const int tid = threadIdx.x;
  hist[tid] = 0;
  __syncthreads();
  const int base = blockIdx.x * 4096;
#pragma unroll
  for (int j = 0; j < 16; ++j) {
    int i = base + j * 256 + tid;
    if (i < E) atomicAdd(&hist[((unsigned int)col[i]) >> 8], 1);
  }
  __syncthreads();
  if (tid < NBK) {
    int h = hist[tid];
    if (h) atomicAdd(&bucket_count[tid], h);
  }
}

// Single block: exclusive scan of NBK (<=256) bucket counts.
__global__ __launch_bounds__(256) void scan_buckets_kernel(const int* __restrict__ bucket_count,
                                                           int* __restrict__ bucket_start,
                                                           int* __restrict__ bcur,
                                                           int* __restrict__ offs_n, int NBK,
                                                           int E) {
  __shared__ int ws[4];
  const int tid = threadIdx.x;
  const int lane = tid & 63;
  const int wid = tid >> 6;
  int v = (tid < NBK) ? bucket_count[tid] : 0;
  int incl = v;
#pragma unroll
  for (int d = 1; d < 64; d <<= 1) {
    int t = __shfl_up(incl, d, 64);
    if (lane >= d) incl += t;
  }
  if (lane == 63) ws[wid] = incl;
  __syncthreads();
  int woff = 0;
#pragma unroll
  for (int w = 0; w < 4; ++w)
    if (w < wid) woff += ws[w];
  int excl = woff + incl - v;
  if (tid < NBK) {
    bucket_start[tid] = excl;
    bcur[tid] = excl;
  }
  if (tid == 0) {
    bucket_start[NBK] = E;
    *offs_n = E;
  }
}

// ------------------------------- MFMA GEMM body ----------------------------
template <int K, int N, bool ABF16, bool OUTF16>
__device__ __forceinline__ void gemm_body(const void* __restrict__ Ap,
                                          const unsigned short* __restrict__ Bfrag,
                                          unsigned short* __restrict__ Cout, int M, int bid,
                                          int tid) {
  constexpr int KS = K / 32;
  constexpr int NT = N / 16;
  const int lane = tid & 63;
  const int wid = tid >> 6;
  const int quad = lane >> 4;
  const int lc = lane & 15;
  const int mbase = bid * 128 + wid * 32;
  if (mbase >= M) return;

  f32x4 acc[2][NT];
#pragma unroll
  for (int mt = 0; mt < 2; ++mt)
#pragma unroll
    for (int nt = 0; nt < NT; ++nt) acc[mt][nt] = (f32x4){0.f, 0.f, 0.f, 0.f};

  int r0 = mbase + lc;
  int r1 = mbase + 16 + lc;
  if (r0 >= M) r0 = M - 1;
  if (r1 >= M) r1 = M - 1;

#pragma unroll
  for (int ks = 0; ks < KS; ++ks) {
    const int k0 = ks * 32 + quad * 8;
    short8x a[2];
    if constexpr (ABF16) {
      const unsigned short* A = (const unsigned short*)Ap;
      a[0] = *(const short8x*)(A + (size_t)r0 * K + k0);
      a[1] = *(const short8x*)(A + (size_t)r1 * K + k0);
    } else {
      const float* A = (const float*)Ap;
      const float4* p0 = (const float4*)(A + (size_t)r0 * K + k0);
      const float4* p1 = (const float4*)(A + (size_t)r1 * K + k0);
      float4 u0 = p0[0], v0 = p0[1];
      float4 u1 = p1[0], v1 = p1[1];
      short8x t0, t1;
      t0[0] = (short)f2bf(u0.x); t0[1] = (short)f2bf(u0.y);
      t0[2] = (short)f2bf(u0.z); t0[3] = (short)f2bf(u0.w);
      t0[4] = (short)f2bf(v0.x); t0[5] = (short)f2bf(v0.y);
      t0[6] = (short)f2bf(v0.z); t0[7] = (short)f2bf(v0.w);
      t1[0] = (short)f2bf(u1.x); t1[1] = (short)f2bf(u1.y);
      t1[2] = (short)f2bf(u1.z); t1[3] = (short)f2bf(u1.w);
      t1[4] = (short)f2bf(v1.x); t1[5] = (short)f2bf(v1.y);
      t1[6] = (short)f2bf(v1.z); t1[7] = (short)f2bf(v1.w);
      a[0] = t0;
      a[1] = t1;
    }
#pragma unroll
    for (int nt = 0; nt < NT; ++nt) {
      short8x b = *(const short8x*)(Bfrag + (((size_t)nt * KS + ks) * 64 + lane) * 8);
      acc[0][nt] = __builtin_amdgcn_mfma_f32_16x16x32_bf16(a[0], b, acc[0][nt], 0, 0, 0);
      acc[1][nt] = __builtin_amdgcn_mfma_f32_16x16x32_bf16(a[1], b, acc[1][nt], 0, 0, 0);
    }
  }

#pragma unroll
  for (int mt = 0; mt < 2; ++mt)
#pragma unroll
    for (int nt = 0; nt < NT; ++nt)
#pragma unroll
      for (int reg = 0; reg < 4; ++reg) {
        int row = mbase + mt * 16 + quad * 4 + reg;
        if (row < M) {
          float v = acc[mt][nt][reg];
          Cout[(size_t)row * N + nt * 16 + lc] = OUTF16 ? f2h(v) : f2bf(v);
        }
      }
}

template <int K, int N, bool ABF16, bool OUTF16>
__global__ __launch_bounds__(256) void mfma_gemm_kernel(const void* __restrict__ Ap,
                                                        const unsigned short* __restrict__ Bfrag,
                                                        unsigned short* __restrict__ Cout, int M) {
  gemm_body<K, N, ABF16, OUTF16>(Ap, Bfrag, Cout, M, blockIdx.x, threadIdx.x);
}

// binA_scatter (+fused GEMM1 in extra blocks): 4096 edges/block; LDS hist ->
// one global atomicAdd per (block,bucket) reserve -> LDS-cursor scatter of
// packed (col<<16|row). GEMM1 blocks (blockIdx >= NAB) run the layer-1
// x@W1 MFMA GEMM concurrently (independent work, different pipes).
__global__ __launch_bounds__(256) void scatter_gemm_kernel(
    const int* __restrict__ row, const int* __restrict__ col, int* __restrict__ bcur,
    unsigned int* __restrict__ staging, int E, int NBK, int NAB, const float* __restrict__ x,
    const unsigned short* __restrict__ bfW1, unsigned short* __restrict__ xw1, int M) {
  __shared__ int hist[256];
  if ((int)blockIdx.x >= NAB) {
    gemm_body<512, 128, false, false>(x, bfW1, xw1, M, (int)blockIdx.x - NAB, threadIdx.x);
    return;
  }
  const int tid = threadIdx.x;
  hist[tid] = 0;
  __syncthreads();
  const int base = blockIdx.x * 4096;
  unsigned int payload[16];
  int bk[16];
#pragma unroll
  for (int j = 0; j < 16; ++j) {
    int i = base + j * 256 + tid;
    if (i < E) {
      unsigned int c = (unsigned int)__builtin_nontemporal_load(&col[i]);
      unsigned int r = (unsigned int)__builtin_nontemporal_load(&row[i]);
      payload[j] = (c << 16) | r;
      bk[j] = (int)(c >> 8);
      atomicAdd(&hist[bk[j]], 1);
    } else {
      bk[j] = -1;
    }
  }
  __syncthreads();
  if (tid < NBK) {
    int h = hist[tid];
    hist[tid] = h ? atomicAdd(&bcur[tid], h) : 0;
  }
  __syncthreads();
#pragma unroll
  for (int j = 0; j < 16; ++j) {
    if (bk[j] >= 0) {
      int p = atomicAdd(&hist[bk[j]], 1);
      staging[p] = payload[j];
    }
  }
}

// binB1: one block per 256-node bucket. LDS node-histogram of the bucket's
// staging segment -> LDS scan -> writes offs[node] and dinv[node].
__global__ __launch_bounds__(256) void binB1_kernel(const unsigned int* __restrict__ staging,
                                                    const int* __restrict__ bucket_start,
                                                    int* __restrict__ offs,
                                                    float* __restrict__ dinv, int N) {
  __shared__ int cnt[256];
  __shared__ int ws[4];
  const int b = blockIdx.x;
  const int n0 = b * 256;
  const int tid = threadIdx.x;
  cnt[tid] = 0;
  __syncthreads();
  const int s = bucket_start[b];
  const int e = bucket_start[b + 1];
  for (int t = s + tid; t < e; t += 256) {
    atomicAdd(&cnt[(staging[t] >> 16) & 255u], 1);
  }
  __syncthreads();
  const int deg = cnt[tid];
  const int lane = tid & 63;
  const int wid = tid >> 6;
  int incl = deg;
#pragma unroll
  for (int d = 1; d < 64; d <<= 1) {
    int t = __shfl_up(incl, d, 64);
    if (lane >= d) incl += t;
  }
  if (lane == 63) ws[wid] = incl;
  __syncthreads();
  int woff = 0;
#pragma unroll
  for (int w = 0; w < 4; ++w)
    if (w < wid) woff += ws[w];
  const int excl = woff + incl - deg;
  const int node = n0 + tid;
  if (node < N) {
    offs[node] = s + excl;
    dinv[node] = rsqrtf((float)deg + 1.0f);
  }
}

// binB2: fine scatter into CSR with packed bf16 dinv.
__global__ __launch_bounds__(512) void binB2_kernel(const unsigned int* __restrict__ staging,
                                                    const int* __restrict__ offs,
                                                    const int* __restrict__ bucket_start,
                                                    const float* __restrict__ dinv,
                                                    unsigned int* __restrict__ csr, int N) {
  __shared__ int cur[256];
  const int b = blockIdx.x;
  const int n0 = b * 256;
  const int tid = threadIdx.x;
  if (tid < 256 && n0 + tid < N) cur[tid] = offs[n0 + tid];
  __syncthreads();
  const int s = bucket_start[b];
  const int e = bucket_start[b + 1];
  for (int t = s + tid; t < e; t += 512) {
    unsigned int v = __builtin_nontemporal_load(&staging[t]);
    int cl = (int)((v >> 16) & 255u);
    unsigned int r = v & 0xFFFFu;
    unsigned int wd = f2bf(dinv[r]);
    int p = atomicAdd(&cur[cl], 1);
    csr[p] = (wd << 16) | r;
  }
}

// ------------------ aggregation (8B-lane gather, packed FMA) ---------------
// RD = dwords per feature row. G = RD/2 lanes per node; each lane owns one
// dwordx2 (4 bf16 feats). 16-deep edge batching; miss-path-bound (frozen).
template <int RD>
__global__ __launch_bounds__(256) void agg_fast_kernel(
    const unsigned short* __restrict__ xw, const int* __restrict__ offs,
    const unsigned int* __restrict__ csr, const float* __restrict__ dinv,
    const float* __restrict__ bias, const float* __restrict__ gamma,
    const float* __restrict__ beta, const float* __restrict__ mean,
    const float* __restrict__ var, unsigned short* __restrict__ out, int N) {
  constexpr int G = RD / 2;  // lanes per node (uint2x each)
  constexpr int NPB = 256 / G;
  const int li = threadIdx.x % G;
  const int i = blockIdx.x * NPB + threadIdx.x / G;
  if (i >= N) return;
  const uint2x* xw64 = (const uint2x*)xw;  // row stride = G uint2x
  const float di = dinv[i];
  const int s = offs[i], e = offs[i + 1];
  float2x acc0 = {0.f, 0.f};  // feats (4li, 4li+1)
  float2x acc1 = {0.f, 0.f};  // feats (4li+2, 4li+3)
  int t = s;
  for (; t + 16 <= e; t += 16) {
    unsigned int ent[16];
#pragma unroll
    for (int j = 0; j < 16; ++j) ent[j] = __builtin_nontemporal_load(&csr[t + j]);
    uint2x gv[16];
#pragma unroll
    for (int j = 0; j < 16; ++j) gv[j] = xw64[(size_t)(ent[j] & 0xFFFFu) * G + li];
#pragma unroll
    for (int j = 0; j < 16; ++j) {
      float w = __uint_as_float(ent[j] & 0xFFFF0000u);
      float2x wv = {w, w};
      float2x x0 = {__uint_as_float(gv[j].x << 16), __uint_as_float(gv[j].x & 0xFFFF0000u)};
      float2x x1 = {__uint_as_float(gv[j].y << 16), __uint_as_float(gv[j].y & 0xFFFF0000u)};
      acc0 = __builtin_elementwise_fma(wv, x0, acc0);
      acc1 = __builtin_elementwise_fma(wv, x1, acc1);
    }
  }
  for (; t + 4 <= e; t += 4) {
    unsigned int ent[4];
#pragma unroll
    for (int j = 0; j < 4; ++j) ent[j] = __builtin_nontemporal_load(&csr[t + j]);
    uint2x gv[4];
#pragma unroll
    for (int j = 0; j < 4; ++j) gv[j] = xw64[(size_t)(ent[j] & 0xFFFFu) * G + li];
#pragma unroll
    for (int j = 0; j < 4; ++j) {
      float w = __uint_as_float(ent[j] & 0xFFFF0000u);
      float2x wv = {w, w};
      float2x x0 = {__uint_as_float(gv[j].x << 16), __uint_as_float(gv[j].x & 0xFFFF0000u)};
      float2x x1 = {__uint_as_float(gv[j].y << 16), __uint_as_float(gv[j].y & 0xFFFF0000u)};
      acc0 = __builtin_elementwise_fma(wv, x0, acc0);
      acc1 = __builtin_elementwise_fma(wv, x1, acc1);
    }
  }
  for (; t < e; ++t) {
    unsigned int ee = __builtin_nontemporal_load(&csr[t]);
    uint2x gv = xw64[(size_t)(ee & 0xFFFFu) * G + li];
    float w = __uint_as_float(ee & 0xFFFF0000u);
    float2x wv = {w, w};
    float2x x0 = {__uint_as_float(gv.x << 16), __uint_as_float(gv.x & 0xFFFF0000u)};
    float2x x1 = {__uint_as_float(gv.y << 16), __uint_as_float(gv.y & 0xFFFF0000u)};
    acc0 = __builtin_elementwise_fma(wv, x0, acc0);
    acc1 = __builtin_elementwise_fma(wv, x1, acc1);
  }
  const int f0 = 4 * li;
  uint2x sv = xw64[(size_t)i * G + li];
  float sl0 = __uint_as_float(sv.x << 16), sh0 = __uint_as_float(sv.x & 0xFFFF0000u);
  float sl1 = __uint_as_float(sv.y << 16), sh1 = __uint_as_float(sv.y & 0xFFFF0000u);
  const float dd = di * di;
  float v0 = di * acc0.x + dd * sl0 + bias[f0 + 0];
  float v1 = di * acc0.y + dd * sh0 + bias[f0 + 1];
  float v2 = di * acc1.x + dd * sl1 + bias[f0 + 2];
  float v3 = di * acc1.y + dd * sh1 + bias[f0 + 3];
  v0 = (v0 - mean[f0 + 0]) * rsqrtf(var[f0 + 0] + 1e-5f) * gamma[f0 + 0] + beta[f0 + 0];
  v1 = (v1 - mean[f0 + 1]) * rsqrtf(var[f0 + 1] + 1e-5f) * gamma[f0 + 1] + beta[f0 + 1];
  v2 = (v2 - mean[f0 + 2]) * rsqrtf(var[f0 + 2] + 1e-5f) * gamma[f0 + 2] + beta[f0 + 2];
  v3 = (v3 - mean[f0 + 3]) * rsqrtf(var[f0 + 3] + 1e-5f) * gamma[f0 + 3] + beta[f0 + 3];
  uint2x packed;
  packed.x = (unsigned int)f2bf(fmaxf(v0, 0.f)) | ((unsigned int)f2bf(fmaxf(v1, 0.f)) << 16);
  packed.y = (unsigned int)f2bf(fmaxf(v2, 0.f)) | ((unsigned int)f2bf(fmaxf(v3, 0.f)) << 16);
  ((uint2x*)out)[(size_t)i * G + li] = packed;
}

// ------------------------------- edge head ---------------------------------
// zh[n] = [za(64 f16) || zb(64 f16)], za = z@hW1_top, zb = z@hW1_bot.
// Per edge: logit = relu(za[s]+zb[d]+hb1) . hW2 + hb2.
// Wave layout: lc = edge-in-chunk (16 edges/wave), quad = 16-feature slice.
// 2 chunks per iteration -> 8 independent 16B gathers in flight per lane.
__global__ __launch_bounds__(256) void head2_kernel(
    const unsigned short* __restrict__ zh, const int* __restrict__ src,
    const int* __restrict__ dst, const float* __restrict__ hb1,
    const float* __restrict__ hw2, const float* __restrict__ hb2,
    float* __restrict__ out, int P) {
  const int lane = threadIdx.x & 63;
  const int lc = lane & 15;
  const int quad = lane >> 4;
  float b1v[16], w2v[16];
#pragma unroll
  for (int t = 0; t < 16; ++t) {
    b1v[t] = hb1[quad * 16 + t];
    w2v[t] = hw2[quad * 16 + t];
  }
  const float bias2 = hb2[0];
  const int nchunks = (P + 15) / 16;
  const int npair = (nchunks + 1) / 2;
  const int gw = blockIdx.x * 4 + (threadIdx.x >> 6);
  const int nw = gridDim.x * 4;

  for (int cp = gw; cp < npair; cp += nw) {
    const int ch0 = cp * 2;
    const int ch1 = ch0 + 1;
    const bool has1 = ch1 < nchunks;
    int p0 = ch0 * 16 + lc;
    int p1 = (has1 ? ch1 : ch0) * 16 + lc;
    int pc0 = p0 < P ? p0 : P - 1;
    int pc1 = p1 < P ? p1 : P - 1;
    int s0 = __builtin_nontemporal_load(&src[pc0]);
    int d0 = __builtin_nontemporal_load(&dst[pc0]);
    int s1 = __builtin_nontemporal_load(&src[pc1]);
    int d1 = __builtin_nontemporal_load(&dst[pc1]);
    const half8x* pa0 = (const half8x*)(zh + (size_t)s0 * 128 + quad * 16);
    const half8x* pb0 = (const half8x*)(zh + (size_t)d0 * 128 + 64 + quad * 16);
    const half8x* pa1 = (const half8x*)(zh + (size_t)s1 * 128 + quad * 16);
    const half8x* pb1 = (const half8x*)(zh + (size_t)d1 * 128 + 64 + quad * 16);
    half8x a00 = pa0[0], a01 = pa0[1];
    half8x b00 = pb0[0], b01 = pb0[1];
    half8x a10 = pa1[0], a11 = pa1[1];
    half8x b10 = pb1[0], b11 = pb1[1];
    float acc0 = 0.f, acc1 = 0.f;
#pragma unroll
    for (int t = 0; t < 8; ++t) {
      acc0 = fmaf(fmaxf((float)a00[t] + (float)b00[t] + b1v[t], 0.f), w2v[t], acc0);
      acc1 = fmaf(fmaxf((float)a10[t] + (float)b10[t] + b1v[t], 0.f), w2v[t], acc1);
    }
#pragma unroll
    for (int t = 0; t < 8; ++t) {
      acc0 = fmaf(fmaxf((float)a01[t] + (float)b01[t] + b1v[8 + t], 0.f), w2v[8 + t], acc0);
      acc1 = fmaf(fmaxf((float)a11[t] + (float)b11[t] + b1v[8 + t], 0.f), w2v[8 + t], acc1);
    }
    acc0 += __shfl_xor(acc0, 16, 64);
    acc0 += __shfl_xor(acc0, 32, 64);
    acc1 += __shfl_xor(acc1, 16, 64);
    acc1 += __shfl_xor(acc1, 32, 64);
    if (quad == 0) {
      if (p0 < P) {
        float o = 1.0f / (1.0f + __expf(-(acc0 + bias2)));
        __builtin_nontemporal_store(o, &out[p0]);
      }
      if (has1 && p1 < P) {
        float o = 1.0f / (1.0f + __expf(-(acc1 + bias2)));
        __builtin_nontemporal_store(o, &out[p1]);
      }
    }
  }
}

// ------------------------------- launcher ----------------------------------

extern "C" void kernel_launch(void* const* d_in, const int* in_sizes, int n_in,
                              void* d_out, int out_size, void* d_ws, size_t ws_size,
                              hipStream_t stream) {
  const float* x = (const float*)d_in[0];
  const int* ei = (const int*)d_in[1];
  const int* src = (const int*)d_in[2];
  const int* dst = (const int*)d_in[3];
  const float* W1 = (const float*)d_in[4];
  const float* b1 = (const float*)d_in[5];
  const float* g1 = (const float*)d_in[6];
  const float* be1 = (const float*)d_in[7];
  const float* mu1 = (const float*)d_in[8];
  const float* va1 = (const float*)d_in[9];
  const float* W2 = (const float*)d_in[10];
  const float* b2 = (const float*)d_in[11];
  const float* g2 = (const float*)d_in[12];
  const float* be2 = (const float*)d_in[13];
  const float* mu2 = (const float*)d_in[14];
  const float* va2 = (const float*)d_in[15];
  const float* hW1 = (const float*)d_in[16];
  const float* hb1 = (const float*)d_in[17];
  const float* hW2 = (const float*)d_in[18];
  const float* hb2 = (const float*)d_in[19];
  float* out = (float*)d_out;

  const int N = in_sizes[0] / 512;
  const int E = in_sizes[1] / 2;
  const int P = in_sizes[2];
  const int* row = ei;
  const int* col = ei + E;
  const int NBK = (N + 255) / 256;    // buckets (256 nodes each), <=256
  const int NAB = (E + 4095) / 4096;  // binA blocks
  const int NGB = (N + 127) / 128;    // GEMM blocks over nodes

  char* wp = (char*)d_ws;
  auto alloc = [&](size_t bytes) {
    char* p = wp;
    wp += (bytes + 255) & ~(size_t)255;
    return p;
  };
  unsigned short* xw1 = (unsigned short*)alloc((size_t)N * 128 * 2);
  unsigned short* h = (unsigned short*)alloc((size_t)N * 128 * 2);
  unsigned short* xw2 = (unsigned short*)alloc((size_t)N * 64 * 2);
  unsigned short* z = (unsigned short*)alloc((size_t)N * 64 * 2);
  unsigned short* zh = (unsigned short*)alloc((size_t)N * 128 * 2);  // f16 [za||zb]
  float* dinv = (float*)alloc((size_t)N * 4);
  int* offs = (int*)alloc((size_t)(N + 1) * 4);
  unsigned int* csr = (unsigned int*)alloc((size_t)E * 4);
  unsigned int* staging = (unsigned int*)alloc((size_t)E * 4);
  int* bucket_count = (int*)alloc((size_t)NBK * 4);
  int* bucket_start = (int*)alloc((size_t)(NBK + 1) * 4);
  int* bcur = (int*)alloc((size_t)NBK * 4);
  unsigned short* bfW1 = (unsigned short*)alloc(512 * 128 * 2);
  unsigned short* bfW2 = (unsigned short*)alloc(128 * 64 * 2);
  unsigned short* bfH = (unsigned short*)alloc(128 * 64 * 2);
  (void)ws_size;
  (void)n_in;
  (void)out_size;

  // --- graph structure + weight prep (fused into spare blocks) ---
  hipLaunchKernelGGL(zero_int_kernel, dim3((NBK + 255) / 256), dim3(256), 0, stream, bucket_count,
                     NBK);
  hipLaunchKernelGGL(hist_prep_kernel, dim3(NAB + 40), dim3(256), 0, stream, col, bucket_count, E,
                     NBK, NAB, W1, W2, hW1, bfW1, bfW2, bfH);
  hipLaunchKernelGGL(scan_buckets_kernel, dim3(1), dim3(256), 0, stream, bucket_count,
                     bucket_start, bcur, offs + N, NBK, E);
  // --- edge scatter || layer-1 GEMM (independent; different pipes) ---
  hipLaunchKernelGGL(scatter_gemm_kernel, dim3(NAB + NGB), dim3(256), 0, stream, row, col, bcur,
                     staging, E, NBK, NAB, x, bfW1, xw1, N);
  hipLaunchKernelGGL(binB1_kernel, dim3(NBK), dim3(256), 0, stream, staging, bucket_start, offs,
                     dinv, N);
  hipLaunchKernelGGL(binB2_kernel, dim3(NBK), dim3(512), 0, stream, staging, offs, bucket_start,
                     dinv, csr, N);

  // --- layer 1 aggregation ---
  hipLaunchKernelGGL((agg_fast_kernel<64>), dim3((N + 7) / 8), dim3(256), 0, stream, xw1, offs,
                     csr, dinv, b1, g1, be1, mu1, va1, h, N);

  // --- layer 2 ---
  hipLaunchKernelGGL((mfma_gemm_kernel<128, 64, true, false>), dim3(NGB), dim3(256), 0, stream, h,
                     bfW2, xw2, N);
  hipLaunchKernelGGL((agg_fast_kernel<32>), dim3((N + 15) / 16), dim3(256), 0, stream, xw2, offs,
                     csr, dinv, b2, g2, be2, mu2, va2, z, N);

  // --- edge head: node-side GEMM then per-edge add/relu/dot ---
  hipLaunchKernelGGL((mfma_gemm_kernel<64, 128, true, true>), dim3(NGB), dim3(256), 0, stream, z,
                     bfH, zh, N);
  hipLaunchKernelGGL(head2_kernel, dim3(4096), dim3(256), 0, stream, zh, src, dst, hb1, hW2, hb2,
                     out, P);
}